// Round 5
// baseline (198.838 us; speedup 1.0000x reference)
//
#include <hip/hip_runtime.h>

// ---------------------------------------------------------------------------
// QuantumImageEncoder R16: halve LDS-port traffic via 2 channels per thread.
//  R15 post-mortem: conflicts fixed (6.5M->1.5M) but conv only 95->90us.
//  Issue-slot math: ~33% per-SIMD VALU issue; LDS port (1 per CU, shared by
//  4 SIMDs) is ~saturated: P2~147 + P3~672 + P5~400 wave-b128/block x 12cyc
//  x 16 blocks/CU ~ available cycles. The port traffic is 8-16x redundant
//  across output channels (lanes with same colgroup read identical bytes).
//  R16: each thread computes TWO channels per LDS read:
//   P2: tasks (chpair 4, colgroup 7, row 14), 2 k-iters -> 73 wave-b128.
//   P3: tasks (ocpair 8, colgroup 4, row 7), single pass  -> 336 wave-b128.
//  Same FMA count, half the port transactions. acc = 32 VGPR/thread; no
//  launch-bounds min clamp (R12 lesson).
// ---------------------------------------------------------------------------

#define B_EPS 1e-5f

typedef float f2 __attribute__((ext_vector_type(2)));

__device__ __forceinline__ f2 sp(float x)          { f2 r; r.x = x; r.y = x; return r; }
__device__ __forceinline__ f2 mk(float a, float b) { f2 r; r.x = a; r.y = b; return r; }
#define PKFMA(a, b, c) __builtin_elementwise_fma(a, b, c)
#define PKMAX(a, b)    __builtin_elementwise_max(a, b)

// 3-tap conv row update: acc[j] += wp[0..2] * rv[j..j+2]  (packed, 2 samples)
__device__ __forceinline__ void row_fma(f2* acc, const float* wp, const f2* rv)
{
    #pragma unroll
    for (int j = 0; j < 4; j++) {
        acc[j] = PKFMA(sp(wp[0]), rv[j],     acc[j]);
        acc[j] = PKFMA(sp(wp[1]), rv[j + 1], acc[j]);
        acc[j] = PKFMA(sp(wp[2]), rv[j + 2], acc[j]);
    }
}

// load 6 consecutive f2 from 16B-aligned base as 3x b128
__device__ __forceinline__ void load_rv6(f2* rv, const f2* rp)
{
    float4 A = *(const float4*)rp;
    float4 Bv = *(const float4*)(rp + 2);
    float4 Cv = *(const float4*)(rp + 4);
    rv[0] = mk(A.x, A.y);   rv[1] = mk(A.z, A.w);
    rv[2] = mk(Bv.x, Bv.y); rv[3] = mk(Bv.z, Bv.w);
    rv[4] = mk(Cv.x, Cv.y); rv[5] = mk(Cv.z, Cv.w);
}

// ---------------- prep: U build + stats zero + conv2-weight repack (block 0),
// ----------------       fc1_w -> wT2[k4][64][4] (blocks 1..196) -------------
__global__ void prep_kernel(const float* __restrict__ rl,
                            const float* __restrict__ f1w,
                            const float* __restrict__ c2w,
                            float* __restrict__ Uout,
                            float* __restrict__ wT2,
                            float* __restrict__ w2q,
                            float* __restrict__ stats)
{
    if (blockIdx.x == 0) {
        __shared__ float2 U[16][16];
        int t = threadIdx.x;                 // 256 threads
        int r = t >> 4, cc = t & 15;
        U[r][cc] = (r == cc) ? make_float2(1.f, 0.f) : make_float2(0.f, 0.f);
        stats[t] = 0.f;                      // 512-float sharded stats
        stats[t + 256] = 0.f;
        // conv2 weights -> w2q[(ci*16+c2)*12 + q], q<9 valid, float4-aligned
        for (int i = t; i < 16 * 8 * 12; i += 256) {
            int ci = i / 192, rem = i - ci * 192;
            int c2 = rem / 12, qq = rem - c2 * 12;
            w2q[i] = (qq < 9) ? c2w[c2 * 72 + ci * 9 + qq] : 0.f;
        }
        __syncthreads();
        for (int op = 0; op < 30; op++) {
            int kind = op & 3;               // 0=rx,1=ry,2=rz,3=cnot ; wire = op%4
            float2 cur = U[r][cc];
            float2 nv;
            if (kind == 3) {
                float2 part = U[r ^ 8][cc];  // control wire3 (bit 1), target wire0 (bit 8)
                nv = (r & 1) ? part : cur;
            } else {
                int m = 8 >> kind;           // wire w=kind -> bit (3-w)
                float theta = rl[op - (op >> 2)];
                float ch = cosf(0.5f * theta), sh = sinf(0.5f * theta);
                float2 part = U[r ^ m][cc];
                int br = (r & m) ? 1 : 0;
                float2 gc, gp;
                if (kind == 0)      { gc = make_float2(ch, 0.f);           gp = make_float2(0.f, -sh); }
                else if (kind == 1) { gc = make_float2(ch, 0.f);           gp = make_float2(br ? sh : -sh, 0.f); }
                else                { gc = make_float2(ch, br ? sh : -sh); gp = make_float2(0.f, 0.f); }
                nv.x = gc.x*cur.x - gc.y*cur.y + gp.x*part.x - gp.y*part.y;
                nv.y = gc.x*cur.y + gc.y*cur.x + gp.x*part.y + gp.y*part.x;
            }
            __syncthreads();
            U[r][cc] = nv;
            __syncthreads();
        }
        ((float2*)Uout)[t] = U[r][cc];
    } else {
        int id = (blockIdx.x - 1) * 256 + threadIdx.x;
        if (id < 784 * 64) {
            int k = id >> 6, o = id & 63;
            // wT2 float index = (k4*64 + o)*4 + (k&3)
            wT2[(((k >> 2) * 64 + o) << 2) + (k & 3)] = f1w[o * 784 + k];
        }
    }
}

// ---------------- conv backbone + fused fc: 2 samples / block, 4 waves ------
// All activations are f2 = (sample0, sample1). One packed FMA covers both.
// Tiles store col c at idx c+3 so conv windows (col-1..col+4) are 16B-aligned.
__global__ __launch_bounds__(256) void conv_kernel(
    const float* __restrict__ x,  const float* __restrict__ c1w,
    const float* __restrict__ c1b, const float* __restrict__ w2q,
    const float* __restrict__ c2b, const float* __restrict__ wT2,
    const float* __restrict__ f1b, const float* __restrict__ f2w,
    const float* __restrict__ f2bias, float* __restrict__ feat,
    float* __restrict__ stats)
{
    __shared__ union alignas(16) {
        f2 xin[30 * 32];           // [row 0..29][idx]; col c -> idx c+3, halo zeros
        f2 flat[784];              // conv2 pooled output, idx = c2*49 + i*7 + pc
    } u;
    __shared__ union alignas(16) {
        f2 p1[8 * 290];            // [ch][row 0..15 (stride 18)][idx]; col c -> idx c+3
        struct { f2 part[4][64]; f2 hs[64]; } fc;   // p1 dead after P3
    } pu;

    int t = threadIdx.x;
    int w = t >> 6, lane = t & 63;

    // P2 task decode: lane = [r2][chpair p][colgroup g]
    int r2 = lane >> 5;            // row parity within wave
    int p2p = (lane >> 3) & 3;     // conv1 channel pair
    int g  = lane & 7;             // col group (g<7 active)

    // conv1 weights for this lane's TWO channels (16 lanes share an address
    // -> L1 broadcast). Issued before staging so latency is covered.
    int chA = 2 * p2p, chB = 2 * p2p + 1;
    float wkA[9], wkB[9];
    #pragma unroll
    for (int q = 0; q < 9; q++) { wkA[q] = c1w[chA * 9 + q]; wkB[q] = c1w[chB * 9 + q]; }
    float biasA = c1b[chA], biasB = c1b[chB];

    // ---- P1: zero xin + p1 (halo correctness)
    {
        float4 z = make_float4(0.f, 0.f, 0.f, 0.f);
        float4* xz = (float4*)u.xin;
        for (int i = t; i < 480; i += 256) xz[i] = z;       // 960 f2
        float4* pz = (float4*)pu.p1;
        for (int i = t; i < 1160; i += 256) pz[i] = z;      // 2320 f2
    }
    __syncthreads();

    // ---- stage input: both samples interleaved (col c -> idx c+3)
    {
        const float4* xg0 = (const float4*)(x + (size_t)blockIdx.x * 2 * 784);
        const float4* xg1 = xg0 + 196;
        if (t < 196) {
            float4 v0 = xg0[t];
            float4 v1 = xg1[t];
            int pp = 4 * t, rr = pp / 28, cb = pp - rr * 28;  // cb in {0,4,...,24}
            f2* dst = &u.xin[(rr + 1) * 32 + cb + 3];
            dst[0] = mk(v0.x, v1.x);
            dst[1] = mk(v0.y, v1.y);
            dst[2] = mk(v0.z, v1.z);
            dst[3] = mk(v0.w, v1.w);
        }
    }
    __syncthreads();

    // ---- P2: conv1 + relu + pool -> p1. Thread owns (chpair, colgroup, row);
    // rows i = w*2 + r2 + 8k. One rv load feeds 2 channels (half port traffic).
    {
        if (g < 7) {
            const f2* xb = &u.xin[4 * g + 2];               // even idx: 16B aligned
            #pragma unroll 1
            for (int k = 0; k < 2; k++) {
                int i = w * 2 + r2 + 8 * k;                 // pooled row 0..15
                if (i > 13) break;                          // wave-uniform skip
                f2 oA[2][4], oB[2][4];
                #pragma unroll
                for (int dr = 0; dr < 2; dr++)
                    #pragma unroll
                    for (int j = 0; j < 4; j++) { oA[dr][j] = sp(biasA); oB[dr][j] = sp(biasB); }
                #pragma unroll
                for (int q = 0; q < 4; q++) {               // stored row 2i+q
                    f2 rv[6];
                    load_rv6(rv, xb + (2 * i + q) * 32);
                    if (q < 3)  { row_fma(oA[0], &wkA[q * 3], rv);
                                  row_fma(oB[0], &wkB[q * 3], rv); }
                    if (q >= 1) { row_fma(oA[1], &wkA[(q - 1) * 3], rv);
                                  row_fma(oB[1], &wkB[(q - 1) * 3], rv); }
                }
                f2* poutA = &pu.p1[chA * 290 + 3 + (i + 1) * 18 + 2 * g];
                f2* poutB = &pu.p1[chB * 290 + 3 + (i + 1) * 18 + 2 * g];
                #pragma unroll
                for (int jj = 0; jj < 2; jj++) {
                    f2 mA = PKMAX(PKMAX(oA[0][2 * jj], oA[0][2 * jj + 1]),
                                  PKMAX(oA[1][2 * jj], oA[1][2 * jj + 1]));
                    f2 mB = PKMAX(PKMAX(oB[0][2 * jj], oB[0][2 * jj + 1]),
                                  PKMAX(oB[1][2 * jj], oB[1][2 * jj + 1]));
                    poutA[jj] = PKMAX(mA, sp(0.f));
                    poutB[jj] = PKMAX(mB, sp(0.f));
                }
            }
        }
    }
    __syncthreads();

    // ---- P3: conv2 + relu + pool -> u.flat (xin dead). Thread owns
    // (ocpair, colgroup, row): 224 tasks, single pass. One rv load feeds
    // 2 output channels. Weights from global w2q (L1-resident).
    if (t < 224) {
        int i3  = t >> 5;            // pooled row 0..6
        int p3  = (t >> 2) & 7;      // oc pair
        int g2  = t & 3;             // col group
        int cA = 2 * p3, cB = 2 * p3 + 1;
        const float4* wqA = (const float4*)w2q + cA * 3;    // + ci*48 per ci
        const float4* wqB = (const float4*)w2q + cB * 3;
        f2 accA[2][4], accB[2][4];
        {
            float bA = c2b[cA], bB = c2b[cB];
            #pragma unroll
            for (int dr = 0; dr < 2; dr++)
                #pragma unroll
                for (int j = 0; j < 4; j++) { accA[dr][j] = sp(bA); accB[dr][j] = sp(bB); }
        }
        #pragma unroll 1
        for (int ci = 0; ci < 8; ci++) {
            float4 a0 = wqA[ci * 48], a1 = wqA[ci * 48 + 1], a2 = wqA[ci * 48 + 2];
            float4 b0 = wqB[ci * 48], b1 = wqB[ci * 48 + 1], b2 = wqB[ci * 48 + 2];
            float wA[9] = {a0.x, a0.y, a0.z, a0.w, a1.x, a1.y, a1.z, a1.w, a2.x};
            float wB[9] = {b0.x, b0.y, b0.z, b0.w, b1.x, b1.y, b1.z, b1.w, b2.x};
            // even idx base (16B aligned); g2=3 overruns into zero halo /
            // discarded outputs only.
            const f2* pc_ = &pu.p1[ci * 290 + (2 * i3) * 18 + 4 * g2 + 2];
            #pragma unroll
            for (int q = 0; q < 4; q++) {                   // stored row 2i+q
                f2 rv[6];
                load_rv6(rv, pc_ + q * 18);
                if (q < 3)  { row_fma(accA[0], &wA[q * 3], rv);
                              row_fma(accB[0], &wB[q * 3], rv); }
                if (q >= 1) { row_fma(accA[1], &wA[(q - 1) * 3], rv);
                              row_fma(accB[1], &wB[(q - 1) * 3], rv); }
            }
        }
        #pragma unroll
        for (int jj = 0; jj < 2; jj++) {
            int pc = 2 * g2 + jj;
            if (pc < 7) {
                f2 mA = PKMAX(PKMAX(accA[0][2 * jj], accA[0][2 * jj + 1]),
                              PKMAX(accA[1][2 * jj], accA[1][2 * jj + 1]));
                f2 mB = PKMAX(PKMAX(accB[0][2 * jj], accB[0][2 * jj + 1]),
                              PKMAX(accB[1][2 * jj], accB[1][2 * jj + 1]));
                u.flat[cA * 49 + i3 * 7 + pc] = PKMAX(mA, sp(0.f));
                u.flat[cB * 49 + i3 * 7 + pc] = PKMAX(mB, sp(0.f));
            }
        }
    }
    __syncthreads();   // p1 dead from here; pu.fc live

    // ---- P5: fc1 partials. wave owns g-quarter [w*49, w*49+49); weight
    // float4 (global, read once/block) feeds one packed chain for 2 samples.
    {
        const f2* fl = u.flat;
        const float4* wp4 = (const float4*)wT2 + lane;      // + g*64 per k4-group
        int g0 = w * 49;
        f2 a0 = sp(0.f), a1 = sp(0.f);
        #pragma unroll 2
        for (int gg = g0; gg < g0 + 48; gg += 2) {
            float4 wv0 = wp4[(size_t)gg * 64];
            float4 wv1 = wp4[(size_t)(gg + 1) * 64];
            float4 fA = *(const float4*)&fl[4 * gg];
            float4 fB = *(const float4*)&fl[4 * gg + 2];
            float4 fC = *(const float4*)&fl[4 * gg + 4];
            float4 fD = *(const float4*)&fl[4 * gg + 6];
            a0 = PKFMA(sp(wv0.x), mk(fA.x, fA.y), a0);
            a0 = PKFMA(sp(wv0.y), mk(fA.z, fA.w), a0);
            a0 = PKFMA(sp(wv0.z), mk(fB.x, fB.y), a0);
            a0 = PKFMA(sp(wv0.w), mk(fB.z, fB.w), a0);
            a1 = PKFMA(sp(wv1.x), mk(fC.x, fC.y), a1);
            a1 = PKFMA(sp(wv1.y), mk(fC.z, fC.w), a1);
            a1 = PKFMA(sp(wv1.z), mk(fD.x, fD.y), a1);
            a1 = PKFMA(sp(wv1.w), mk(fD.z, fD.w), a1);
        }
        {   // tail group g0+48
            int gg = g0 + 48;
            float4 wv = wp4[(size_t)gg * 64];
            float4 fA = *(const float4*)&fl[4 * gg];
            float4 fB = *(const float4*)&fl[4 * gg + 2];
            a0 = PKFMA(sp(wv.x), mk(fA.x, fA.y), a0);
            a0 = PKFMA(sp(wv.y), mk(fA.z, fA.w), a0);
            a0 = PKFMA(sp(wv.z), mk(fB.x, fB.y), a0);
            a0 = PKFMA(sp(wv.w), mk(fB.z, fB.w), a0);
        }
        pu.fc.part[w][lane] = a0 + a1;
    }
    __syncthreads();

    // ---- P6: combine quarters + bias + relu (both samples packed)
    if (t < 64) {
        f2 h = pu.fc.part[0][t] + pu.fc.part[1][t]
             + pu.fc.part[2][t] + pu.fc.part[3][t] + sp(f1b[t]);
        pu.fc.hs[t] = PKMAX(h, sp(0.f));
    }
    __syncthreads();

    // ---- P7: fc2 + feat + sharded BN stats (packed: .x=s0, .y=s1)
    if (t < 4) {
        int j = t;
        f2 a = sp(f2bias[j]);
        #pragma unroll
        for (int o = 0; o < 64; o++) a = PKFMA(sp(f2w[j * 64 + o]), pu.fc.hs[o], a);
        feat[((size_t)blockIdx.x * 2 + 0) * 4 + j] = a.x;
        feat[((size_t)blockIdx.x * 2 + 1) * 4 + j] = a.y;
        int g2 = blockIdx.x & 63;
        atomicAdd(&stats[g2 * 8 + j], a.x + a.y);
        atomicAdd(&stats[g2 * 8 + 4 + j], a.x * a.x + a.y * a.y);
    }
}

// ---------------- BN + encoder + U matvec + PauliZ measure ------------------
// 4 lanes per sample (each does 4 rows of the 16x16 matvec, shfl-reduce).
__global__ __launch_bounds__(128) void quantum_kernel(
    const float* __restrict__ feat, const float* __restrict__ Ug,
    const float* __restrict__ stats, const float* __restrict__ bn_g,
    const float* __restrict__ bn_b, float* __restrict__ out, int B)
{
    __shared__ float2 Us[256];
    __shared__ float sm[8];
    int t = threadIdx.x;                  // 128 threads
    for (int i = t; i < 256; i += 128) Us[i] = ((const float2*)Ug)[i];
    if (t < 8) sm[t] = 0.f;
    __syncthreads();
    {   // parallel gather of 64 shards x 8 (index mod 8 preserved by +128)
        float v = stats[t] + stats[t + 128] + stats[t + 256] + stats[t + 384];
        atomicAdd(&sm[t & 7], v);
    }
    __syncthreads();
    int q = t & 3;                        // row-quad within the sample
    int s = blockIdx.x * 32 + (t >> 2);
    float4 fv = ((const float4*)feat)[s];
    float f[4] = {fv.x, fv.y, fv.z, fv.w};
    float cn[4], sn[4];
    float invB = 1.0f / (float)B;
    #pragma unroll
    for (int w = 0; w < 4; w++) {
        float mean = sm[w] * invB;
        float var  = sm[4 + w] * invB - mean * mean;
        float fh = (f[w] - mean) / sqrtf(var + B_EPS) * bn_g[w] + bn_b[w];
        cn[w] = cosf(0.5f * fh);
        sn[w] = sinf(0.5f * fh);
    }
    // encoded product state: s0_k = prod(c/s) * (-i)^popcount(k)
    float re0[16], im0[16];
    #pragma unroll
    for (int k = 0; k < 16; k++) {
        float mag = ((k & 8) ? sn[0] : cn[0]) * ((k & 4) ? sn[1] : cn[1]) *
                    ((k & 2) ? sn[2] : cn[2]) * ((k & 1) ? sn[3] : cn[3]);
        int m = __popc(k) & 3;
        re0[k] = (m == 0) ? mag : (m == 2) ? -mag : 0.f;
        im0[k] = (m == 1) ? -mag : (m == 3) ? mag : 0.f;
    }
    float o0 = 0.f, o1 = 0.f, o2 = 0.f, o3 = 0.f;
    #pragma unroll
    for (int i = 0; i < 4; i++) {
        int r = q * 4 + i;
        float ar = 0.f, ai = 0.f;
        #pragma unroll
        for (int k = 0; k < 16; k++) {
            float2 uu = Us[r * 16 + k];
            ar += uu.x * re0[k] - uu.y * im0[k];
            ai += uu.x * im0[k] + uu.y * re0[k];
        }
        float pqr = ar * ar + ai * ai;
        o0 += (r & 8) ? -pqr : pqr;
        o1 += (r & 4) ? -pqr : pqr;
        o2 += (r & 2) ? -pqr : pqr;
        o3 += (r & 1) ? -pqr : pqr;
    }
    // reduce across the 4-lane group
    o0 += __shfl_xor(o0, 1);  o0 += __shfl_xor(o0, 2);
    o1 += __shfl_xor(o1, 1);  o1 += __shfl_xor(o1, 2);
    o2 += __shfl_xor(o2, 1);  o2 += __shfl_xor(o2, 2);
    o3 += __shfl_xor(o3, 1);  o3 += __shfl_xor(o3, 2);
    if (q == 0) {
        float4 ov = {o0, o1, o2, o3};
        ((float4*)out)[s] = ov;
    }
}

// ---------------------------------------------------------------------------
extern "C" void kernel_launch(void* const* d_in, const int* in_sizes, int n_in,
                              void* d_out, int out_size, void* d_ws, size_t ws_size,
                              hipStream_t stream)
{
    const float* x   = (const float*)d_in[0];
    const float* c1w = (const float*)d_in[1];
    const float* c1b = (const float*)d_in[2];
    const float* c2w = (const float*)d_in[3];
    const float* c2b = (const float*)d_in[4];
    const float* f1w = (const float*)d_in[5];
    const float* f1b = (const float*)d_in[6];
    const float* f2w = (const float*)d_in[7];
    const float* f2b = (const float*)d_in[8];
    const float* bng = (const float*)d_in[9];
    const float* bnb = (const float*)d_in[10];
    const float* rl  = (const float*)d_in[11];
    float* out = (float*)d_out;

    int B = in_sizes[0] / 784;

    float* wsf   = (float*)d_ws;
    float* feat  = wsf;                          // B*4
    float* wT2   = feat + (size_t)B * 4;         // 784*64 (as [k4][64][4])
    float* U     = wT2 + 784 * 64;               // 512 (float2[256])
    float* stats = U + 512;                      // 512 (64 shards x 8)
    float* w2q   = stats + 512;                  // 1536 ([ci][c2][12], q<9 used)

    prep_kernel<<<197, 256, 0, stream>>>(rl, f1w, c2w, U, wT2, w2q, stats);
    conv_kernel<<<B / 2, 256, 0, stream>>>(x, c1w, c1b, w2q, c2b, wT2,
                                           f1b, f2w, f2b, feat, stats);
    quantum_kernel<<<B / 32, 128, 0, stream>>>(feat, U, stats, bng, bnb, out, B);
}

// Round 6
// 193.459 us; speedup vs baseline: 1.0278x; 1.0278x over previous
//
#include <hip/hip_runtime.h>

// ---------------------------------------------------------------------------
// QuantumImageEncoder R17: R15 base (90us conv) + forced v_pk_fma_f32 and
// hoisted weight broadcasts.
//  R16 post-mortem: halving LDS-port traffic REGRESSED (occ 52->34 via VGPR
//  40->64); across R14-R16 dur*VALUBusy is constant -> conv is VALU-cycle
//  bound at ~71% busy ceiling. Lever = fewer VALU instructions at equal
//  occupancy:
//   1) row_fma now uses inline-asm v_pk_fma_f32 (VOP3P, reg-pair operands).
//      If the builtin was scalarizing, this halves FMA cycles.
//   2) conv weights pre-broadcast to f2 pairs ONCE per phase (was: sp(w)
//      re-broadcast per row_fma call, ~350 calls x 3 movs per wave).
//  Structure, layouts, occupancy knobs identical to R15.
// ---------------------------------------------------------------------------

#define B_EPS 1e-5f

typedef float f2 __attribute__((ext_vector_type(2)));

__device__ __forceinline__ f2 sp(float x)          { f2 r; r.x = x; r.y = x; return r; }
__device__ __forceinline__ f2 mk(float a, float b) { f2 r; r.x = a; r.y = b; return r; }
#define PKFMA(a, b, c) __builtin_elementwise_fma(a, b, c)
#define PKMAX(a, b)    __builtin_elementwise_max(a, b)

// forced packed fma: acc += a*b (one VOP3P instruction, 2 samples)
__device__ __forceinline__ void pk_fma(f2& acc, f2 a, f2 b)
{
    asm("v_pk_fma_f32 %0, %1, %2, %0" : "+v"(acc) : "v"(a), "v"(b));
}

// 3-tap conv row update: acc[j] += wp[0..2] * rv[j..j+2]; wp pre-broadcast f2
__device__ __forceinline__ void row_fma(f2* acc, const f2* wp, const f2* rv)
{
    #pragma unroll
    for (int j = 0; j < 4; j++) {
        pk_fma(acc[j], wp[0], rv[j]);
        pk_fma(acc[j], wp[1], rv[j + 1]);
        pk_fma(acc[j], wp[2], rv[j + 2]);
    }
}

// load 6 consecutive f2 from 16B-aligned base as 3x b128
__device__ __forceinline__ void load_rv6(f2* rv, const f2* rp)
{
    float4 A = *(const float4*)rp;
    float4 Bv = *(const float4*)(rp + 2);
    float4 Cv = *(const float4*)(rp + 4);
    rv[0] = mk(A.x, A.y);   rv[1] = mk(A.z, A.w);
    rv[2] = mk(Bv.x, Bv.y); rv[3] = mk(Bv.z, Bv.w);
    rv[4] = mk(Cv.x, Cv.y); rv[5] = mk(Cv.z, Cv.w);
}

// ---------------- prep: U build + stats zero + conv2-weight repack (block 0),
// ----------------       fc1_w -> wT2[k4][64][4] (blocks 1..196) -------------
__global__ void prep_kernel(const float* __restrict__ rl,
                            const float* __restrict__ f1w,
                            const float* __restrict__ c2w,
                            float* __restrict__ Uout,
                            float* __restrict__ wT2,
                            float* __restrict__ w2q,
                            float* __restrict__ stats)
{
    if (blockIdx.x == 0) {
        __shared__ float2 U[16][16];
        int t = threadIdx.x;                 // 256 threads
        int r = t >> 4, cc = t & 15;
        U[r][cc] = (r == cc) ? make_float2(1.f, 0.f) : make_float2(0.f, 0.f);
        stats[t] = 0.f;                      // 512-float sharded stats
        stats[t + 256] = 0.f;
        // conv2 weights -> w2q[(ci*16+c2)*12 + q], q<9 valid, float4-aligned
        for (int i = t; i < 16 * 8 * 12; i += 256) {
            int ci = i / 192, rem = i - ci * 192;
            int c2 = rem / 12, qq = rem - c2 * 12;
            w2q[i] = (qq < 9) ? c2w[c2 * 72 + ci * 9 + qq] : 0.f;
        }
        __syncthreads();
        for (int op = 0; op < 30; op++) {
            int kind = op & 3;               // 0=rx,1=ry,2=rz,3=cnot ; wire = op%4
            float2 cur = U[r][cc];
            float2 nv;
            if (kind == 3) {
                float2 part = U[r ^ 8][cc];  // control wire3 (bit 1), target wire0 (bit 8)
                nv = (r & 1) ? part : cur;
            } else {
                int m = 8 >> kind;           // wire w=kind -> bit (3-w)
                float theta = rl[op - (op >> 2)];
                float ch = cosf(0.5f * theta), sh = sinf(0.5f * theta);
                float2 part = U[r ^ m][cc];
                int br = (r & m) ? 1 : 0;
                float2 gc, gp;
                if (kind == 0)      { gc = make_float2(ch, 0.f);           gp = make_float2(0.f, -sh); }
                else if (kind == 1) { gc = make_float2(ch, 0.f);           gp = make_float2(br ? sh : -sh, 0.f); }
                else                { gc = make_float2(ch, br ? sh : -sh); gp = make_float2(0.f, 0.f); }
                nv.x = gc.x*cur.x - gc.y*cur.y + gp.x*part.x - gp.y*part.y;
                nv.y = gc.x*cur.y + gc.y*cur.x + gp.x*part.y + gp.y*part.x;
            }
            __syncthreads();
            U[r][cc] = nv;
            __syncthreads();
        }
        ((float2*)Uout)[t] = U[r][cc];
    } else {
        int id = (blockIdx.x - 1) * 256 + threadIdx.x;
        if (id < 784 * 64) {
            int k = id >> 6, o = id & 63;
            // wT2 float index = (k4*64 + o)*4 + (k&3)
            wT2[(((k >> 2) * 64 + o) << 2) + (k & 3)] = f1w[o * 784 + k];
        }
    }
}

// ---------------- conv backbone + fused fc: 2 samples / block, 4 waves ------
// All activations are f2 = (sample0, sample1). One packed FMA covers both.
// Tiles store col c at idx c+3 so conv windows (col-1..col+4) are 16B-aligned.
__global__ __launch_bounds__(256) void conv_kernel(
    const float* __restrict__ x,  const float* __restrict__ c1w,
    const float* __restrict__ c1b, const float* __restrict__ w2q,
    const float* __restrict__ c2b, const float* __restrict__ wT2,
    const float* __restrict__ f1b, const float* __restrict__ f2w,
    const float* __restrict__ f2bias, float* __restrict__ feat,
    float* __restrict__ stats)
{
    __shared__ union alignas(16) {
        f2 xin[30 * 32];           // [row 0..29][idx]; col c -> idx c+3, halo zeros
        f2 flat[784];              // conv2 pooled output, idx = c2*49 + i*7 + pc
    } u;
    __shared__ union alignas(16) {
        f2 p1[8 * 290];            // [ch][row 0..15 (stride 18)][idx]; col c -> idx c+3
        struct { f2 part[4][64]; f2 hs[64]; } fc;   // p1 dead after P3
    } pu;

    int t = threadIdx.x;
    int w = t >> 6, lane = t & 63;

    // conv1 weights for this lane (8 lanes share an address -> L1 broadcast),
    // pre-broadcast to f2 pairs once.
    int c1 = lane >> 3;
    f2 wk1p[9];
    #pragma unroll
    for (int q = 0; q < 9; q++) wk1p[q] = sp(c1w[c1 * 9 + q]);
    float bias1 = c1b[c1];

    // ---- P1: zero xin + p1 (halo correctness)
    {
        float4 z = make_float4(0.f, 0.f, 0.f, 0.f);
        float4* xz = (float4*)u.xin;
        for (int i = t; i < 480; i += 256) xz[i] = z;       // 960 f2
        float4* pz = (float4*)pu.p1;
        for (int i = t; i < 1160; i += 256) pz[i] = z;      // 2320 f2
    }
    __syncthreads();

    // ---- stage input: both samples interleaved (col c -> idx c+3)
    {
        const float4* xg0 = (const float4*)(x + (size_t)blockIdx.x * 2 * 784);
        const float4* xg1 = xg0 + 196;
        if (t < 196) {
            float4 v0 = xg0[t];
            float4 v1 = xg1[t];
            int p = 4 * t, rr = p / 28, cb = p - rr * 28;   // cb in {0,4,...,24}
            f2* dst = &u.xin[(rr + 1) * 32 + cb + 3];
            dst[0] = mk(v0.x, v1.x);
            dst[1] = mk(v0.y, v1.y);
            dst[2] = mk(v0.z, v1.z);
            dst[3] = mk(v0.w, v1.w);
        }
    }
    __syncthreads();

    // ---- P2: conv1 + relu + pool -> p1. wave w owns pooled rows {w+4k}.
    // lane=(c1,g): channel c1, 4-col group g (g<7). 3x b128 per input row.
    {
        int g = lane & 7;
        if (g < 7) {
            const f2* xb = &u.xin[4 * g + 2];               // even idx: 16B aligned
            f2* pout = &pu.p1[c1 * 290 + 3];
            #pragma unroll 1
            for (int k = 0; k < 4; k++) {
                int i = w + 4 * k;                          // pooled row 0..13
                if (i > 13) break;
                f2 o_[2][4];
                #pragma unroll
                for (int dr = 0; dr < 2; dr++)
                    #pragma unroll
                    for (int j = 0; j < 4; j++) o_[dr][j] = sp(bias1);
                #pragma unroll
                for (int q = 0; q < 4; q++) {               // stored row 2i+q
                    f2 rv[6];
                    load_rv6(rv, xb + (2 * i + q) * 32);
                    if (q < 3)  row_fma(o_[0], &wk1p[q * 3], rv);        // dr=0, ky=q
                    if (q >= 1) row_fma(o_[1], &wk1p[(q - 1) * 3], rv);  // dr=1, ky=q-1
                }
                #pragma unroll
                for (int jj = 0; jj < 2; jj++) {
                    f2 m = PKMAX(PKMAX(o_[0][2 * jj], o_[0][2 * jj + 1]),
                                 PKMAX(o_[1][2 * jj], o_[1][2 * jj + 1]));
                    pout[(i + 1) * 18 + 2 * g + jj] = PKMAX(m, sp(0.f));
                }
            }
        }
    }
    __syncthreads();

    // ---- P3: conv2 + relu + pool -> u.flat (xin dead). wave w owns pooled
    // rows {w, w+4}. lane=(c2,g2). Weights from global w2q (L1), prefetched,
    // broadcast to f2 pairs once per ci (9 movs instead of 18).
    {
        int c2 = lane >> 2, g2 = lane & 3;
        float bias2 = c2b[c2];
        const float4* wqb = (const float4*)w2q + c2 * 3;    // + ci*48 per ci
        #pragma unroll 1
        for (int k = 0; k < 2; k++) {
            int i = w + 4 * k;                              // pooled row 0..6
            if (i > 6) break;
            f2 acc[2][4];
            #pragma unroll
            for (int dr = 0; dr < 2; dr++)
                #pragma unroll
                for (int j = 0; j < 4; j++) acc[dr][j] = sp(bias2);
            float4 wa = wqb[0], wb = wqb[1], wc = wqb[2];
            #pragma unroll 1
            for (int ci = 0; ci < 8; ci++) {
                f2 wkp[9];
                wkp[0] = sp(wa.x); wkp[1] = sp(wa.y); wkp[2] = sp(wa.z);
                wkp[3] = sp(wa.w); wkp[4] = sp(wb.x); wkp[5] = sp(wb.y);
                wkp[6] = sp(wb.z); wkp[7] = sp(wb.w); wkp[8] = sp(wc.x);
                if (ci < 7) {                               // prefetch next ci
                    wa = wqb[(ci + 1) * 48];
                    wb = wqb[(ci + 1) * 48 + 1];
                    wc = wqb[(ci + 1) * 48 + 2];
                }
                // even idx base (16B aligned); g2=3 overruns 2 f2 into the
                // next row's zero halo -> feeds only discarded outputs.
                const f2* pc_ = &pu.p1[ci * 290 + (2 * i) * 18 + 4 * g2 + 2];
                #pragma unroll
                for (int q = 0; q < 4; q++) {               // stored row 2i+q
                    f2 rv[6];
                    load_rv6(rv, pc_ + q * 18);
                    if (q < 3)  row_fma(acc[0], &wkp[q * 3], rv);
                    if (q >= 1) row_fma(acc[1], &wkp[(q - 1) * 3], rv);
                }
            }
            #pragma unroll
            for (int jj = 0; jj < 2; jj++) {
                int pc = 2 * g2 + jj;
                if (pc < 7) {
                    f2 m = PKMAX(PKMAX(acc[0][2 * jj], acc[0][2 * jj + 1]),
                                 PKMAX(acc[1][2 * jj], acc[1][2 * jj + 1]));
                    u.flat[c2 * 49 + i * 7 + pc] = PKMAX(m, sp(0.f));
                }
            }
        }
    }
    __syncthreads();   // p1 dead from here; pu.fc live

    // ---- P5: fc1 partials. wave owns g-quarter [w*49, w*49+49); weight
    // float4 (global, read once/block) feeds one packed chain for 2 samples.
    {
        const f2* fl = u.flat;
        const float4* wp4 = (const float4*)wT2 + lane;      // + g*64 per k4-group
        int g0 = w * 49;
        f2 a0 = sp(0.f), a1 = sp(0.f);
        #pragma unroll 2
        for (int g = g0; g < g0 + 48; g += 2) {
            float4 wv0 = wp4[(size_t)g * 64];
            float4 wv1 = wp4[(size_t)(g + 1) * 64];
            float4 fA = *(const float4*)&fl[4 * g];
            float4 fB = *(const float4*)&fl[4 * g + 2];
            float4 fC = *(const float4*)&fl[4 * g + 4];
            float4 fD = *(const float4*)&fl[4 * g + 6];
            pk_fma(a0, sp(wv0.x), mk(fA.x, fA.y));
            pk_fma(a0, sp(wv0.y), mk(fA.z, fA.w));
            pk_fma(a0, sp(wv0.z), mk(fB.x, fB.y));
            pk_fma(a0, sp(wv0.w), mk(fB.z, fB.w));
            pk_fma(a1, sp(wv1.x), mk(fC.x, fC.y));
            pk_fma(a1, sp(wv1.y), mk(fC.z, fC.w));
            pk_fma(a1, sp(wv1.z), mk(fD.x, fD.y));
            pk_fma(a1, sp(wv1.w), mk(fD.z, fD.w));
        }
        {   // tail group g0+48
            int g = g0 + 48;
            float4 wv = wp4[(size_t)g * 64];
            float4 fA = *(const float4*)&fl[4 * g];
            float4 fB = *(const float4*)&fl[4 * g + 2];
            pk_fma(a0, sp(wv.x), mk(fA.x, fA.y));
            pk_fma(a0, sp(wv.y), mk(fA.z, fA.w));
            pk_fma(a0, sp(wv.z), mk(fB.x, fB.y));
            pk_fma(a0, sp(wv.w), mk(fB.z, fB.w));
        }
        pu.fc.part[w][lane] = a0 + a1;
    }
    __syncthreads();

    // ---- P6: combine quarters + bias + relu (both samples packed)
    if (t < 64) {
        f2 h = pu.fc.part[0][t] + pu.fc.part[1][t]
             + pu.fc.part[2][t] + pu.fc.part[3][t] + sp(f1b[t]);
        pu.fc.hs[t] = PKMAX(h, sp(0.f));
    }
    __syncthreads();

    // ---- P7: fc2 + feat + sharded BN stats (packed: .x=s0, .y=s1)
    if (t < 4) {
        int j = t;
        f2 a = sp(f2bias[j]);
        #pragma unroll
        for (int o = 0; o < 64; o++) pk_fma(a, sp(f2w[j * 64 + o]), pu.fc.hs[o]);
        feat[((size_t)blockIdx.x * 2 + 0) * 4 + j] = a.x;
        feat[((size_t)blockIdx.x * 2 + 1) * 4 + j] = a.y;
        int g = blockIdx.x & 63;
        atomicAdd(&stats[g * 8 + j], a.x + a.y);
        atomicAdd(&stats[g * 8 + 4 + j], a.x * a.x + a.y * a.y);
    }
}

// ---------------- BN + encoder + U matvec + PauliZ measure ------------------
// 4 lanes per sample (each does 4 rows of the 16x16 matvec, shfl-reduce).
__global__ __launch_bounds__(128) void quantum_kernel(
    const float* __restrict__ feat, const float* __restrict__ Ug,
    const float* __restrict__ stats, const float* __restrict__ bn_g,
    const float* __restrict__ bn_b, float* __restrict__ out, int B)
{
    __shared__ float2 Us[256];
    __shared__ float sm[8];
    int t = threadIdx.x;                  // 128 threads
    for (int i = t; i < 256; i += 128) Us[i] = ((const float2*)Ug)[i];
    if (t < 8) sm[t] = 0.f;
    __syncthreads();
    {   // parallel gather of 64 shards x 8 (index mod 8 preserved by +128)
        float v = stats[t] + stats[t + 128] + stats[t + 256] + stats[t + 384];
        atomicAdd(&sm[t & 7], v);
    }
    __syncthreads();
    int q = t & 3;                        // row-quad within the sample
    int s = blockIdx.x * 32 + (t >> 2);
    float4 fv = ((const float4*)feat)[s];
    float f[4] = {fv.x, fv.y, fv.z, fv.w};
    float cn[4], sn[4];
    float invB = 1.0f / (float)B;
    #pragma unroll
    for (int w = 0; w < 4; w++) {
        float mean = sm[w] * invB;
        float var  = sm[4 + w] * invB - mean * mean;
        float fh = (f[w] - mean) / sqrtf(var + B_EPS) * bn_g[w] + bn_b[w];
        cn[w] = cosf(0.5f * fh);
        sn[w] = sinf(0.5f * fh);
    }
    // encoded product state: s0_k = prod(c/s) * (-i)^popcount(k)
    float re0[16], im0[16];
    #pragma unroll
    for (int k = 0; k < 16; k++) {
        float mag = ((k & 8) ? sn[0] : cn[0]) * ((k & 4) ? sn[1] : cn[1]) *
                    ((k & 2) ? sn[2] : cn[2]) * ((k & 1) ? sn[3] : cn[3]);
        int m = __popc(k) & 3;
        re0[k] = (m == 0) ? mag : (m == 2) ? -mag : 0.f;
        im0[k] = (m == 1) ? -mag : (m == 3) ? mag : 0.f;
    }
    float o0 = 0.f, o1 = 0.f, o2 = 0.f, o3 = 0.f;
    #pragma unroll
    for (int i = 0; i < 4; i++) {
        int r = q * 4 + i;
        float ar = 0.f, ai = 0.f;
        #pragma unroll
        for (int k = 0; k < 16; k++) {
            float2 uu = Us[r * 16 + k];
            ar += uu.x * re0[k] - uu.y * im0[k];
            ai += uu.x * im0[k] + uu.y * re0[k];
        }
        float p = ar * ar + ai * ai;
        o0 += (r & 8) ? -p : p;
        o1 += (r & 4) ? -p : p;
        o2 += (r & 2) ? -p : p;
        o3 += (r & 1) ? -p : p;
    }
    // reduce across the 4-lane group
    o0 += __shfl_xor(o0, 1);  o0 += __shfl_xor(o0, 2);
    o1 += __shfl_xor(o1, 1);  o1 += __shfl_xor(o1, 2);
    o2 += __shfl_xor(o2, 1);  o2 += __shfl_xor(o2, 2);
    o3 += __shfl_xor(o3, 1);  o3 += __shfl_xor(o3, 2);
    if (q == 0) {
        float4 ov = {o0, o1, o2, o3};
        ((float4*)out)[s] = ov;
    }
}

// ---------------------------------------------------------------------------
extern "C" void kernel_launch(void* const* d_in, const int* in_sizes, int n_in,
                              void* d_out, int out_size, void* d_ws, size_t ws_size,
                              hipStream_t stream)
{
    const float* x   = (const float*)d_in[0];
    const float* c1w = (const float*)d_in[1];
    const float* c1b = (const float*)d_in[2];
    const float* c2w = (const float*)d_in[3];
    const float* c2b = (const float*)d_in[4];
    const float* f1w = (const float*)d_in[5];
    const float* f1b = (const float*)d_in[6];
    const float* f2w = (const float*)d_in[7];
    const float* f2b = (const float*)d_in[8];
    const float* bng = (const float*)d_in[9];
    const float* bnb = (const float*)d_in[10];
    const float* rl  = (const float*)d_in[11];
    float* out = (float*)d_out;

    int B = in_sizes[0] / 784;

    float* wsf   = (float*)d_ws;
    float* feat  = wsf;                          // B*4
    float* wT2   = feat + (size_t)B * 4;         // 784*64 (as [k4][64][4])
    float* U     = wT2 + 784 * 64;               // 512 (float2[256])
    float* stats = U + 512;                      // 512 (64 shards x 8)
    float* w2q   = stats + 512;                  // 1536 ([ci][c2][12], q<9 used)

    prep_kernel<<<197, 256, 0, stream>>>(rl, f1w, c2w, U, wT2, w2q, stats);
    conv_kernel<<<B / 2, 256, 0, stream>>>(x, c1w, c1b, w2q, c2b, wT2,
                                           f1b, f2w, f2b, feat, stats);
    quantum_kernel<<<B / 32, 128, 0, stream>>>(feat, U, stats, bng, bnb, out, B);
}

// Round 7
// 192.066 us; speedup vs baseline: 1.0353x; 1.0072x over previous
//
#include <hip/hip_runtime.h>

// ---------------------------------------------------------------------------
// QuantumImageEncoder R18: R15 base (builtin pk-fma, 90us conv) + compact p1
// -> 7 blocks/CU.
//  R17 post-mortem: builtin already emitted v_pk_fma_f32; inline asm ADDED
//  movs (dur*busy 63.9->77.7). Reverted.
//  Invariant R14-R16: dur*VALUBusy ~= 63.6 us*% -> VALU count fixed, busy%
//  tracks occupancy. R15 = 6 blocks/CU (LDS alloc 26624).
//  R18 shrinks LDS below the 7-block threshold (alloc<=23040):
//   p1: [8ch][14rows x 16 f2 + 2 pad] stride 226 (was 16 rows stride 18+pad):
//   halo ROWS removed via wave-uniform q-skips (i==0&&q==0 / i==6&&q==3);
//   col halos (idx 0/15) zeroed by P1. ky<->q mapping unchanged. Ch stride
//   226 keeps the 4-bank c1 spread (452dw%32=4, same as R15's 290).
//   LDS 7680(xin) + 14496(p1) = 22176 -> alloc 22528 -> 7 blocks/CU.
// ---------------------------------------------------------------------------

#define B_EPS 1e-5f

typedef float f2 __attribute__((ext_vector_type(2)));

__device__ __forceinline__ f2 sp(float x)          { f2 r; r.x = x; r.y = x; return r; }
__device__ __forceinline__ f2 mk(float a, float b) { f2 r; r.x = a; r.y = b; return r; }
#define PKFMA(a, b, c) __builtin_elementwise_fma(a, b, c)
#define PKMAX(a, b)    __builtin_elementwise_max(a, b)

// 3-tap conv row update: acc[j] += wp[0..2] * rv[j..j+2]  (packed, 2 samples)
__device__ __forceinline__ void row_fma(f2* acc, const float* wp, const f2* rv)
{
    #pragma unroll
    for (int j = 0; j < 4; j++) {
        acc[j] = PKFMA(sp(wp[0]), rv[j],     acc[j]);
        acc[j] = PKFMA(sp(wp[1]), rv[j + 1], acc[j]);
        acc[j] = PKFMA(sp(wp[2]), rv[j + 2], acc[j]);
    }
}

// load 6 consecutive f2 from 16B-aligned base as 3x b128
__device__ __forceinline__ void load_rv6(f2* rv, const f2* rp)
{
    float4 A = *(const float4*)rp;
    float4 Bv = *(const float4*)(rp + 2);
    float4 Cv = *(const float4*)(rp + 4);
    rv[0] = mk(A.x, A.y);   rv[1] = mk(A.z, A.w);
    rv[2] = mk(Bv.x, Bv.y); rv[3] = mk(Bv.z, Bv.w);
    rv[4] = mk(Cv.x, Cv.y); rv[5] = mk(Cv.z, Cv.w);
}

// ---------------- prep: U build + stats zero + conv2-weight repack (block 0),
// ----------------       fc1_w -> wT2[k4][64][4] (blocks 1..196) -------------
__global__ void prep_kernel(const float* __restrict__ rl,
                            const float* __restrict__ f1w,
                            const float* __restrict__ c2w,
                            float* __restrict__ Uout,
                            float* __restrict__ wT2,
                            float* __restrict__ w2q,
                            float* __restrict__ stats)
{
    if (blockIdx.x == 0) {
        __shared__ float2 U[16][16];
        int t = threadIdx.x;                 // 256 threads
        int r = t >> 4, cc = t & 15;
        U[r][cc] = (r == cc) ? make_float2(1.f, 0.f) : make_float2(0.f, 0.f);
        stats[t] = 0.f;                      // 512-float sharded stats
        stats[t + 256] = 0.f;
        // conv2 weights -> w2q[(ci*16+c2)*12 + q], q<9 valid, float4-aligned
        for (int i = t; i < 16 * 8 * 12; i += 256) {
            int ci = i / 192, rem = i - ci * 192;
            int c2 = rem / 12, qq = rem - c2 * 12;
            w2q[i] = (qq < 9) ? c2w[c2 * 72 + ci * 9 + qq] : 0.f;
        }
        __syncthreads();
        for (int op = 0; op < 30; op++) {
            int kind = op & 3;               // 0=rx,1=ry,2=rz,3=cnot ; wire = op%4
            float2 cur = U[r][cc];
            float2 nv;
            if (kind == 3) {
                float2 part = U[r ^ 8][cc];  // control wire3 (bit 1), target wire0 (bit 8)
                nv = (r & 1) ? part : cur;
            } else {
                int m = 8 >> kind;           // wire w=kind -> bit (3-w)
                float theta = rl[op - (op >> 2)];
                float ch = cosf(0.5f * theta), sh = sinf(0.5f * theta);
                float2 part = U[r ^ m][cc];
                int br = (r & m) ? 1 : 0;
                float2 gc, gp;
                if (kind == 0)      { gc = make_float2(ch, 0.f);           gp = make_float2(0.f, -sh); }
                else if (kind == 1) { gc = make_float2(ch, 0.f);           gp = make_float2(br ? sh : -sh, 0.f); }
                else                { gc = make_float2(ch, br ? sh : -sh); gp = make_float2(0.f, 0.f); }
                nv.x = gc.x*cur.x - gc.y*cur.y + gp.x*part.x - gp.y*part.y;
                nv.y = gc.x*cur.y + gc.y*cur.x + gp.x*part.y + gp.y*part.x;
            }
            __syncthreads();
            U[r][cc] = nv;
            __syncthreads();
        }
        ((float2*)Uout)[t] = U[r][cc];
    } else {
        int id = (blockIdx.x - 1) * 256 + threadIdx.x;
        if (id < 784 * 64) {
            int k = id >> 6, o = id & 63;
            // wT2 float index = (k4*64 + o)*4 + (k&3)
            wT2[(((k >> 2) * 64 + o) << 2) + (k & 3)] = f1w[o * 784 + k];
        }
    }
}

// ---------------- conv backbone + fused fc: 2 samples / block, 4 waves ------
// All activations are f2 = (sample0, sample1). One packed FMA covers both.
// xin: col c -> idx c+3 (R15). p1 compact: [ch][row 0..13, stride 16][idx],
// col c -> idx c+1, ch stride 226 f2; NO halo rows (wave-uniform q-skips).
__global__ __launch_bounds__(256) void conv_kernel(
    const float* __restrict__ x,  const float* __restrict__ c1w,
    const float* __restrict__ c1b, const float* __restrict__ w2q,
    const float* __restrict__ c2b, const float* __restrict__ wT2,
    const float* __restrict__ f1b, const float* __restrict__ f2w,
    const float* __restrict__ f2bias, float* __restrict__ feat,
    float* __restrict__ stats)
{
    __shared__ union alignas(16) {
        f2 xin[30 * 32];           // [row 0..29][idx]; col c -> idx c+3, halo zeros
        f2 flat[784];              // conv2 pooled output, idx = c2*49 + i*7 + pc
    } u;
    __shared__ union alignas(16) {
        f2 p1[1812];               // [ch][14x16+2pad] stride 226; col c -> idx c+1
        struct { f2 part[4][64]; f2 hs[64]; } fc;   // p1 dead after P3
    } pu;

    int t = threadIdx.x;
    int w = t >> 6, lane = t & 63;

    // conv1 weights for this lane (8 lanes share an address -> L1 broadcast)
    int c1 = lane >> 3;
    float wk1[9];
    #pragma unroll
    for (int q = 0; q < 9; q++) wk1[q] = c1w[c1 * 9 + q];
    float bias1 = c1b[c1];

    // ---- P1: zero xin + p1 (halo correctness: xin ring + p1 col halos)
    {
        float4 z = make_float4(0.f, 0.f, 0.f, 0.f);
        float4* xz = (float4*)u.xin;
        for (int i = t; i < 480; i += 256) xz[i] = z;       // 960 f2
        float4* pz = (float4*)pu.p1;
        for (int i = t; i < 906; i += 256) pz[i] = z;       // 1812 f2
    }
    __syncthreads();

    // ---- stage input: both samples interleaved (col c -> idx c+3)
    {
        const float4* xg0 = (const float4*)(x + (size_t)blockIdx.x * 2 * 784);
        const float4* xg1 = xg0 + 196;
        if (t < 196) {
            float4 v0 = xg0[t];
            float4 v1 = xg1[t];
            int p = 4 * t, rr = p / 28, cb = p - rr * 28;   // cb in {0,4,...,24}
            f2* dst = &u.xin[(rr + 1) * 32 + cb + 3];
            dst[0] = mk(v0.x, v1.x);
            dst[1] = mk(v0.y, v1.y);
            dst[2] = mk(v0.z, v1.z);
            dst[3] = mk(v0.w, v1.w);
        }
    }
    __syncthreads();

    // ---- P2: conv1 + relu + pool -> p1. wave w owns pooled rows {w+4k}.
    // lane=(c1,g): channel c1, 4-col group g (g<7). 3x b128 per input row.
    {
        int g = lane & 7;
        if (g < 7) {
            const f2* xb = &u.xin[4 * g + 2];               // even idx: 16B aligned
            f2* pout = &pu.p1[c1 * 226 + 1];                // col c -> idx c+1
            #pragma unroll 1
            for (int k = 0; k < 4; k++) {
                int i = w + 4 * k;                          // pooled row 0..13
                if (i > 13) break;
                f2 o_[2][4];
                #pragma unroll
                for (int dr = 0; dr < 2; dr++)
                    #pragma unroll
                    for (int j = 0; j < 4; j++) o_[dr][j] = sp(bias1);
                #pragma unroll
                for (int q = 0; q < 4; q++) {               // stored row 2i+q
                    f2 rv[6];
                    load_rv6(rv, xb + (2 * i + q) * 32);
                    if (q < 3)  row_fma(o_[0], &wk1[q * 3], rv);        // dr=0, ky=q
                    if (q >= 1) row_fma(o_[1], &wk1[(q - 1) * 3], rv);  // dr=1, ky=q-1
                }
                #pragma unroll
                for (int jj = 0; jj < 2; jj++) {
                    f2 m = PKMAX(PKMAX(o_[0][2 * jj], o_[0][2 * jj + 1]),
                                 PKMAX(o_[1][2 * jj], o_[1][2 * jj + 1]));
                    pout[i * 16 + 2 * g + jj] = PKMAX(m, sp(0.f));
                }
            }
        }
    }
    __syncthreads();

    // ---- P3: conv2 + relu + pool -> u.flat (xin dead). wave w owns pooled
    // rows {w, w+4}. lane=(c2,g2). Weights from global w2q (L1), prefetched.
    // Input row R = 2i-1+q; R<0 / R>13 skipped (wave-uniform: i uniform,
    // q compile-time) -> halo rows gone from LDS.
    {
        int c2 = lane >> 2, g2 = lane & 3;
        float bias2 = c2b[c2];
        const float4* wqb = (const float4*)w2q + c2 * 3;    // + ci*48 per ci
        #pragma unroll 1
        for (int k = 0; k < 2; k++) {
            int i = w + 4 * k;                              // pooled row 0..6
            if (i > 6) break;
            f2 acc[2][4];
            #pragma unroll
            for (int dr = 0; dr < 2; dr++)
                #pragma unroll
                for (int j = 0; j < 4; j++) acc[dr][j] = sp(bias2);
            float4 wa = wqb[0], wb = wqb[1], wc = wqb[2];
            #pragma unroll 1
            for (int ci = 0; ci < 8; ci++) {
                float wk[9] = {wa.x, wa.y, wa.z, wa.w, wb.x, wb.y, wb.z, wb.w, wc.x};
                if (ci < 7) {                               // prefetch next ci
                    wa = wqb[(ci + 1) * 48];
                    wb = wqb[(ci + 1) * 48 + 1];
                    wc = wqb[(ci + 1) * 48 + 2];
                }
                // base 4g2 even (16B aligned); g2=3 overrun absorbed by the
                // 2-f2 per-ch pad / next-row halo -> discarded outputs only.
                const f2* pc_ = &pu.p1[ci * 226 + 4 * g2];
                #pragma unroll
                for (int q = 0; q < 4; q++) {
                    int R = 2 * i - 1 + q;                  // conv2-input row
                    if (R < 0 || R > 13) continue;          // wave-uniform skip
                    f2 rv[6];
                    load_rv6(rv, pc_ + R * 16);
                    if (q < 3)  row_fma(acc[0], &wk[q * 3], rv);
                    if (q >= 1) row_fma(acc[1], &wk[(q - 1) * 3], rv);
                }
            }
            #pragma unroll
            for (int jj = 0; jj < 2; jj++) {
                int pc = 2 * g2 + jj;
                if (pc < 7) {
                    f2 m = PKMAX(PKMAX(acc[0][2 * jj], acc[0][2 * jj + 1]),
                                 PKMAX(acc[1][2 * jj], acc[1][2 * jj + 1]));
                    u.flat[c2 * 49 + i * 7 + pc] = PKMAX(m, sp(0.f));
                }
            }
        }
    }
    __syncthreads();   // p1 dead from here; pu.fc live

    // ---- P5: fc1 partials. wave owns g-quarter [w*49, w*49+49); weight
    // float4 (global, read once/block) feeds one packed chain for 2 samples.
    {
        const f2* fl = u.flat;
        const float4* wp4 = (const float4*)wT2 + lane;      // + g*64 per k4-group
        int g0 = w * 49;
        f2 a0 = sp(0.f), a1 = sp(0.f);
        #pragma unroll 2
        for (int g = g0; g < g0 + 48; g += 2) {
            float4 wv0 = wp4[(size_t)g * 64];
            float4 wv1 = wp4[(size_t)(g + 1) * 64];
            float4 fA = *(const float4*)&fl[4 * g];
            float4 fB = *(const float4*)&fl[4 * g + 2];
            float4 fC = *(const float4*)&fl[4 * g + 4];
            float4 fD = *(const float4*)&fl[4 * g + 6];
            a0 = PKFMA(sp(wv0.x), mk(fA.x, fA.y), a0);
            a0 = PKFMA(sp(wv0.y), mk(fA.z, fA.w), a0);
            a0 = PKFMA(sp(wv0.z), mk(fB.x, fB.y), a0);
            a0 = PKFMA(sp(wv0.w), mk(fB.z, fB.w), a0);
            a1 = PKFMA(sp(wv1.x), mk(fC.x, fC.y), a1);
            a1 = PKFMA(sp(wv1.y), mk(fC.z, fC.w), a1);
            a1 = PKFMA(sp(wv1.z), mk(fD.x, fD.y), a1);
            a1 = PKFMA(sp(wv1.w), mk(fD.z, fD.w), a1);
        }
        {   // tail group g0+48
            int g = g0 + 48;
            float4 wv = wp4[(size_t)g * 64];
            float4 fA = *(const float4*)&fl[4 * g];
            float4 fB = *(const float4*)&fl[4 * g + 2];
            a0 = PKFMA(sp(wv.x), mk(fA.x, fA.y), a0);
            a0 = PKFMA(sp(wv.y), mk(fA.z, fA.w), a0);
            a0 = PKFMA(sp(wv.z), mk(fB.x, fB.y), a0);
            a0 = PKFMA(sp(wv.w), mk(fB.z, fB.w), a0);
        }
        pu.fc.part[w][lane] = a0 + a1;
    }
    __syncthreads();

    // ---- P6: combine quarters + bias + relu (both samples packed)
    if (t < 64) {
        f2 h = pu.fc.part[0][t] + pu.fc.part[1][t]
             + pu.fc.part[2][t] + pu.fc.part[3][t] + sp(f1b[t]);
        pu.fc.hs[t] = PKMAX(h, sp(0.f));
    }
    __syncthreads();

    // ---- P7: fc2 + feat + sharded BN stats (packed: .x=s0, .y=s1)
    if (t < 4) {
        int j = t;
        f2 a = sp(f2bias[j]);
        #pragma unroll
        for (int o = 0; o < 64; o++) a = PKFMA(sp(f2w[j * 64 + o]), pu.fc.hs[o], a);
        feat[((size_t)blockIdx.x * 2 + 0) * 4 + j] = a.x;
        feat[((size_t)blockIdx.x * 2 + 1) * 4 + j] = a.y;
        int g = blockIdx.x & 63;
        atomicAdd(&stats[g * 8 + j], a.x + a.y);
        atomicAdd(&stats[g * 8 + 4 + j], a.x * a.x + a.y * a.y);
    }
}

// ---------------- BN + encoder + U matvec + PauliZ measure ------------------
// 4 lanes per sample (each does 4 rows of the 16x16 matvec, shfl-reduce).
__global__ __launch_bounds__(128) void quantum_kernel(
    const float* __restrict__ feat, const float* __restrict__ Ug,
    const float* __restrict__ stats, const float* __restrict__ bn_g,
    const float* __restrict__ bn_b, float* __restrict__ out, int B)
{
    __shared__ float2 Us[256];
    __shared__ float sm[8];
    int t = threadIdx.x;                  // 128 threads
    for (int i = t; i < 256; i += 128) Us[i] = ((const float2*)Ug)[i];
    if (t < 8) sm[t] = 0.f;
    __syncthreads();
    {   // parallel gather of 64 shards x 8 (index mod 8 preserved by +128)
        float v = stats[t] + stats[t + 128] + stats[t + 256] + stats[t + 384];
        atomicAdd(&sm[t & 7], v);
    }
    __syncthreads();
    int q = t & 3;                        // row-quad within the sample
    int s = blockIdx.x * 32 + (t >> 2);
    float4 fv = ((const float4*)feat)[s];
    float f[4] = {fv.x, fv.y, fv.z, fv.w};
    float cn[4], sn[4];
    float invB = 1.0f / (float)B;
    #pragma unroll
    for (int w = 0; w < 4; w++) {
        float mean = sm[w] * invB;
        float var  = sm[4 + w] * invB - mean * mean;
        float fh = (f[w] - mean) / sqrtf(var + B_EPS) * bn_g[w] + bn_b[w];
        cn[w] = cosf(0.5f * fh);
        sn[w] = sinf(0.5f * fh);
    }
    // encoded product state: s0_k = prod(c/s) * (-i)^popcount(k)
    float re0[16], im0[16];
    #pragma unroll
    for (int k = 0; k < 16; k++) {
        float mag = ((k & 8) ? sn[0] : cn[0]) * ((k & 4) ? sn[1] : cn[1]) *
                    ((k & 2) ? sn[2] : cn[2]) * ((k & 1) ? sn[3] : cn[3]);
        int m = __popc(k) & 3;
        re0[k] = (m == 0) ? mag : (m == 2) ? -mag : 0.f;
        im0[k] = (m == 1) ? -mag : (m == 3) ? mag : 0.f;
    }
    float o0 = 0.f, o1 = 0.f, o2 = 0.f, o3 = 0.f;
    #pragma unroll
    for (int i = 0; i < 4; i++) {
        int r = q * 4 + i;
        float ar = 0.f, ai = 0.f;
        #pragma unroll
        for (int k = 0; k < 16; k++) {
            float2 uu = Us[r * 16 + k];
            ar += uu.x * re0[k] - uu.y * im0[k];
            ai += uu.x * im0[k] + uu.y * re0[k];
        }
        float p = ar * ar + ai * ai;
        o0 += (r & 8) ? -p : p;
        o1 += (r & 4) ? -p : p;
        o2 += (r & 2) ? -p : p;
        o3 += (r & 1) ? -p : p;
    }
    // reduce across the 4-lane group
    o0 += __shfl_xor(o0, 1);  o0 += __shfl_xor(o0, 2);
    o1 += __shfl_xor(o1, 1);  o1 += __shfl_xor(o1, 2);
    o2 += __shfl_xor(o2, 1);  o2 += __shfl_xor(o2, 2);
    o3 += __shfl_xor(o3, 1);  o3 += __shfl_xor(o3, 2);
    if (q == 0) {
        float4 ov = {o0, o1, o2, o3};
        ((float4*)out)[s] = ov;
    }
}

// ---------------------------------------------------------------------------
extern "C" void kernel_launch(void* const* d_in, const int* in_sizes, int n_in,
                              void* d_out, int out_size, void* d_ws, size_t ws_size,
                              hipStream_t stream)
{
    const float* x   = (const float*)d_in[0];
    const float* c1w = (const float*)d_in[1];
    const float* c1b = (const float*)d_in[2];
    const float* c2w = (const float*)d_in[3];
    const float* c2b = (const float*)d_in[4];
    const float* f1w = (const float*)d_in[5];
    const float* f1b = (const float*)d_in[6];
    const float* f2w = (const float*)d_in[7];
    const float* f2b = (const float*)d_in[8];
    const float* bng = (const float*)d_in[9];
    const float* bnb = (const float*)d_in[10];
    const float* rl  = (const float*)d_in[11];
    float* out = (float*)d_out;

    int B = in_sizes[0] / 784;

    float* wsf   = (float*)d_ws;
    float* feat  = wsf;                          // B*4
    float* wT2   = feat + (size_t)B * 4;         // 784*64 (as [k4][64][4])
    float* U     = wT2 + 784 * 64;               // 512 (float2[256])
    float* stats = U + 512;                      // 512 (64 shards x 8)
    float* w2q   = stats + 512;                  // 1536 ([ci][c2][12], q<9 used)

    prep_kernel<<<197, 256, 0, stream>>>(rl, f1w, c2w, U, wT2, w2q, stats);
    conv_kernel<<<B / 2, 256, 0, stream>>>(x, c1w, c1b, w2q, c2b, wT2,
                                           f1b, f2w, f2b, feat, stats);
    quantum_kernel<<<B / 32, 128, 0, stream>>>(feat, U, stats, bng, bnb, out, B);
}

// Round 8
// 186.941 us; speedup vs baseline: 1.0636x; 1.0274x over previous
//
#include <hip/hip_runtime.h>

// ---------------------------------------------------------------------------
// QuantumImageEncoder R19: R15 verbatim (best: conv 90us / total 185.7us)
// + two additive trims, no structural change.
//  R18 post-mortem: compact-p1 + runtime row-skip branches cost VGPR (40->48)
//  and scheduling; occ FELL 52->44, conv 97.6. Reverted. R16/R17/R18 all
//  lost to R15 -> its phase structure is a local optimum; only additive
//  instruction trims remain:
//   1) zero phase merged into staging: halo-only zeros (xin 116 f2, p1 496
//      f2, disjoint from stage writes) -> one barrier fewer, ~5 fewer LDS
//      stores/thread. g2=3 overread cells beyond halos feed only discarded
//      pc=7 outputs (rv[4..5] -> acc[*][2..3] -> jj=1) -> garbage-safe.
//   2) P7 fc2 on 64 lanes (16/output + shfl reduce) instead of 4 serial.
// ---------------------------------------------------------------------------

#define B_EPS 1e-5f

typedef float f2 __attribute__((ext_vector_type(2)));

__device__ __forceinline__ f2 sp(float x)          { f2 r; r.x = x; r.y = x; return r; }
__device__ __forceinline__ f2 mk(float a, float b) { f2 r; r.x = a; r.y = b; return r; }
#define PKFMA(a, b, c) __builtin_elementwise_fma(a, b, c)
#define PKMAX(a, b)    __builtin_elementwise_max(a, b)

// 3-tap conv row update: acc[j] += wp[0..2] * rv[j..j+2]  (packed, 2 samples)
__device__ __forceinline__ void row_fma(f2* acc, const float* wp, const f2* rv)
{
    #pragma unroll
    for (int j = 0; j < 4; j++) {
        acc[j] = PKFMA(sp(wp[0]), rv[j],     acc[j]);
        acc[j] = PKFMA(sp(wp[1]), rv[j + 1], acc[j]);
        acc[j] = PKFMA(sp(wp[2]), rv[j + 2], acc[j]);
    }
}

// load 6 consecutive f2 from 16B-aligned base as 3x b128
__device__ __forceinline__ void load_rv6(f2* rv, const f2* rp)
{
    float4 A = *(const float4*)rp;
    float4 Bv = *(const float4*)(rp + 2);
    float4 Cv = *(const float4*)(rp + 4);
    rv[0] = mk(A.x, A.y);   rv[1] = mk(A.z, A.w);
    rv[2] = mk(Bv.x, Bv.y); rv[3] = mk(Bv.z, Bv.w);
    rv[4] = mk(Cv.x, Cv.y); rv[5] = mk(Cv.z, Cv.w);
}

// ---------------- prep: U build + stats zero + conv2-weight repack (block 0),
// ----------------       fc1_w -> wT2[k4][64][4] (blocks 1..196) -------------
__global__ void prep_kernel(const float* __restrict__ rl,
                            const float* __restrict__ f1w,
                            const float* __restrict__ c2w,
                            float* __restrict__ Uout,
                            float* __restrict__ wT2,
                            float* __restrict__ w2q,
                            float* __restrict__ stats)
{
    if (blockIdx.x == 0) {
        __shared__ float2 U[16][16];
        int t = threadIdx.x;                 // 256 threads
        int r = t >> 4, cc = t & 15;
        U[r][cc] = (r == cc) ? make_float2(1.f, 0.f) : make_float2(0.f, 0.f);
        stats[t] = 0.f;                      // 512-float sharded stats
        stats[t + 256] = 0.f;
        // conv2 weights -> w2q[(ci*16+c2)*12 + q], q<9 valid, float4-aligned
        for (int i = t; i < 16 * 8 * 12; i += 256) {
            int ci = i / 192, rem = i - ci * 192;
            int c2 = rem / 12, qq = rem - c2 * 12;
            w2q[i] = (qq < 9) ? c2w[c2 * 72 + ci * 9 + qq] : 0.f;
        }
        __syncthreads();
        for (int op = 0; op < 30; op++) {
            int kind = op & 3;               // 0=rx,1=ry,2=rz,3=cnot ; wire = op%4
            float2 cur = U[r][cc];
            float2 nv;
            if (kind == 3) {
                float2 part = U[r ^ 8][cc];  // control wire3 (bit 1), target wire0 (bit 8)
                nv = (r & 1) ? part : cur;
            } else {
                int m = 8 >> kind;           // wire w=kind -> bit (3-w)
                float theta = rl[op - (op >> 2)];
                float ch = cosf(0.5f * theta), sh = sinf(0.5f * theta);
                float2 part = U[r ^ m][cc];
                int br = (r & m) ? 1 : 0;
                float2 gc, gp;
                if (kind == 0)      { gc = make_float2(ch, 0.f);           gp = make_float2(0.f, -sh); }
                else if (kind == 1) { gc = make_float2(ch, 0.f);           gp = make_float2(br ? sh : -sh, 0.f); }
                else                { gc = make_float2(ch, br ? sh : -sh); gp = make_float2(0.f, 0.f); }
                nv.x = gc.x*cur.x - gc.y*cur.y + gp.x*part.x - gp.y*part.y;
                nv.y = gc.x*cur.y + gc.y*cur.x + gp.x*part.y + gp.y*part.x;
            }
            __syncthreads();
            U[r][cc] = nv;
            __syncthreads();
        }
        ((float2*)Uout)[t] = U[r][cc];
    } else {
        int id = (blockIdx.x - 1) * 256 + threadIdx.x;
        if (id < 784 * 64) {
            int k = id >> 6, o = id & 63;
            // wT2 float index = (k4*64 + o)*4 + (k&3)
            wT2[(((k >> 2) * 64 + o) << 2) + (k & 3)] = f1w[o * 784 + k];
        }
    }
}

// ---------------- conv backbone + fused fc: 2 samples / block, 4 waves ------
// All activations are f2 = (sample0, sample1). One packed FMA covers both.
// Tiles store col c at idx c+3 so conv windows (col-1..col+4) are 16B-aligned.
__global__ __launch_bounds__(256) void conv_kernel(
    const float* __restrict__ x,  const float* __restrict__ c1w,
    const float* __restrict__ c1b, const float* __restrict__ w2q,
    const float* __restrict__ c2b, const float* __restrict__ wT2,
    const float* __restrict__ f1b, const float* __restrict__ f2w,
    const float* __restrict__ f2bias, float* __restrict__ feat,
    float* __restrict__ stats)
{
    __shared__ union alignas(16) {
        f2 xin[30 * 32];           // [row 0..29][idx]; col c -> idx c+3, halo zeros
        f2 flat[784];              // conv2 pooled output, idx = c2*49 + i*7 + pc
    } u;
    __shared__ union alignas(16) {
        f2 p1[8 * 290];            // [ch][row 0..15 (stride 18)][idx]; col c -> idx c+3
        struct { f2 part[4][64]; f2 hs[64]; } fc;   // p1 dead after P3
    } pu;

    int t = threadIdx.x;
    int w = t >> 6, lane = t & 63;

    // conv1 weights for this lane (8 lanes share an address -> L1 broadcast)
    int c1 = lane >> 3;
    float wk1[9];
    #pragma unroll
    for (int q = 0; q < 9; q++) wk1[q] = c1w[c1 * 9 + q];
    float bias1 = c1b[c1];

    // ---- P1+stage merged: interior staging + halo-only zeroing (disjoint)
    {
        const float4* xg0 = (const float4*)(x + (size_t)blockIdx.x * 2 * 784);
        const float4* xg1 = xg0 + 196;
        if (t < 196) {
            float4 v0 = xg0[t];
            float4 v1 = xg1[t];
            int p = 4 * t, rr = p / 28, cb = p - rr * 28;   // cb in {0,4,...,24}
            f2* dst = &u.xin[(rr + 1) * 32 + cb + 3];
            dst[0] = mk(v0.x, v1.x);
            dst[1] = mk(v0.y, v1.y);
            dst[2] = mk(v0.z, v1.z);
            dst[3] = mk(v0.w, v1.w);
        }
        f2 z = sp(0.f);
        // xin halo: rows 0 & 29 idx 2..31 (60), rows 1..28 idx {2,31} (56)
        for (int i = t; i < 116; i += 256) {
            int r, c;
            if (i < 60) { r = (i < 30) ? 0 : 29; c = 2 + (i - ((i < 30) ? 0 : 30)); }
            else        { int j = i - 60; r = 1 + (j >> 1); c = (j & 1) ? 31 : 2; }
            u.xin[r * 32 + c] = z;
        }
        // p1 halo per ch (stride 290): rows 0,15 idx 2..17; rows 1..14
        // idx {2,17}; pads idx 288,289  (62 f2 x 8 ch)
        for (int i = t; i < 496; i += 256) {
            int ch = i / 62, j = i - ch * 62, idx;
            if (j < 16)      idx = 2 + j;                        // row 0
            else if (j < 32) idx = 15 * 18 + 2 + (j - 16);       // row 15
            else if (j < 60) { int jj = j - 32;
                               idx = (1 + (jj >> 1)) * 18 + ((jj & 1) ? 17 : 2); }
            else             idx = 288 + (j - 60);               // pads
            pu.p1[ch * 290 + idx] = z;
        }
    }
    __syncthreads();

    // ---- P2: conv1 + relu + pool -> p1. wave w owns pooled rows {w+4k}.
    // lane=(c1,g): channel c1, 4-col group g (g<7). 3x b128 per input row.
    {
        int g = lane & 7;
        if (g < 7) {
            const f2* xb = &u.xin[4 * g + 2];               // even idx: 16B aligned
            f2* pout = &pu.p1[c1 * 290 + 3];
            #pragma unroll 1
            for (int k = 0; k < 4; k++) {
                int i = w + 4 * k;                          // pooled row 0..13
                if (i > 13) break;
                f2 o_[2][4];
                #pragma unroll
                for (int dr = 0; dr < 2; dr++)
                    #pragma unroll
                    for (int j = 0; j < 4; j++) o_[dr][j] = sp(bias1);
                #pragma unroll
                for (int q = 0; q < 4; q++) {               // stored row 2i+q
                    f2 rv[6];
                    load_rv6(rv, xb + (2 * i + q) * 32);
                    if (q < 3)  row_fma(o_[0], &wk1[q * 3], rv);        // dr=0, ky=q
                    if (q >= 1) row_fma(o_[1], &wk1[(q - 1) * 3], rv);  // dr=1, ky=q-1
                }
                #pragma unroll
                for (int jj = 0; jj < 2; jj++) {
                    f2 m = PKMAX(PKMAX(o_[0][2 * jj], o_[0][2 * jj + 1]),
                                 PKMAX(o_[1][2 * jj], o_[1][2 * jj + 1]));
                    pout[(i + 1) * 18 + 2 * g + jj] = PKMAX(m, sp(0.f));
                }
            }
        }
    }
    __syncthreads();

    // ---- P3: conv2 + relu + pool -> u.flat (xin dead). wave w owns pooled
    // rows {w, w+4}. lane=(c2,g2). Weights from global w2q (L1), prefetched.
    {
        int c2 = lane >> 2, g2 = lane & 3;
        float bias2 = c2b[c2];
        const float4* wqb = (const float4*)w2q + c2 * 3;    // + ci*48 per ci
        #pragma unroll 1
        for (int k = 0; k < 2; k++) {
            int i = w + 4 * k;                              // pooled row 0..6
            if (i > 6) break;
            f2 acc[2][4];
            #pragma unroll
            for (int dr = 0; dr < 2; dr++)
                #pragma unroll
                for (int j = 0; j < 4; j++) acc[dr][j] = sp(bias2);
            float4 wa = wqb[0], wb = wqb[1], wc = wqb[2];
            #pragma unroll 1
            for (int ci = 0; ci < 8; ci++) {
                float wk[9] = {wa.x, wa.y, wa.z, wa.w, wb.x, wb.y, wb.z, wb.w, wc.x};
                if (ci < 7) {                               // prefetch next ci
                    wa = wqb[(ci + 1) * 48];
                    wb = wqb[(ci + 1) * 48 + 1];
                    wc = wqb[(ci + 1) * 48 + 2];
                }
                // even idx base (16B aligned); g2=3 overruns 2 f2 into the
                // next row / pads -> feeds only discarded pc=7 outputs.
                const f2* pc_ = &pu.p1[ci * 290 + (2 * i) * 18 + 4 * g2 + 2];
                #pragma unroll
                for (int q = 0; q < 4; q++) {               // stored row 2i+q
                    f2 rv[6];
                    load_rv6(rv, pc_ + q * 18);
                    if (q < 3)  row_fma(acc[0], &wk[q * 3], rv);
                    if (q >= 1) row_fma(acc[1], &wk[(q - 1) * 3], rv);
                }
            }
            #pragma unroll
            for (int jj = 0; jj < 2; jj++) {
                int pc = 2 * g2 + jj;
                if (pc < 7) {
                    f2 m = PKMAX(PKMAX(acc[0][2 * jj], acc[0][2 * jj + 1]),
                                 PKMAX(acc[1][2 * jj], acc[1][2 * jj + 1]));
                    u.flat[c2 * 49 + i * 7 + pc] = PKMAX(m, sp(0.f));
                }
            }
        }
    }
    __syncthreads();   // p1 dead from here; pu.fc live

    // ---- P5: fc1 partials. wave owns g-quarter [w*49, w*49+49); weight
    // float4 (global, read once/block) feeds one packed chain for 2 samples.
    {
        const f2* fl = u.flat;
        const float4* wp4 = (const float4*)wT2 + lane;      // + g*64 per k4-group
        int g0 = w * 49;
        f2 a0 = sp(0.f), a1 = sp(0.f);
        #pragma unroll 2
        for (int g = g0; g < g0 + 48; g += 2) {
            float4 wv0 = wp4[(size_t)g * 64];
            float4 wv1 = wp4[(size_t)(g + 1) * 64];
            float4 fA = *(const float4*)&fl[4 * g];
            float4 fB = *(const float4*)&fl[4 * g + 2];
            float4 fC = *(const float4*)&fl[4 * g + 4];
            float4 fD = *(const float4*)&fl[4 * g + 6];
            a0 = PKFMA(sp(wv0.x), mk(fA.x, fA.y), a0);
            a0 = PKFMA(sp(wv0.y), mk(fA.z, fA.w), a0);
            a0 = PKFMA(sp(wv0.z), mk(fB.x, fB.y), a0);
            a0 = PKFMA(sp(wv0.w), mk(fB.z, fB.w), a0);
            a1 = PKFMA(sp(wv1.x), mk(fC.x, fC.y), a1);
            a1 = PKFMA(sp(wv1.y), mk(fC.z, fC.w), a1);
            a1 = PKFMA(sp(wv1.z), mk(fD.x, fD.y), a1);
            a1 = PKFMA(sp(wv1.w), mk(fD.z, fD.w), a1);
        }
        {   // tail group g0+48
            int g = g0 + 48;
            float4 wv = wp4[(size_t)g * 64];
            float4 fA = *(const float4*)&fl[4 * g];
            float4 fB = *(const float4*)&fl[4 * g + 2];
            a0 = PKFMA(sp(wv.x), mk(fA.x, fA.y), a0);
            a0 = PKFMA(sp(wv.y), mk(fA.z, fA.w), a0);
            a0 = PKFMA(sp(wv.z), mk(fB.x, fB.y), a0);
            a0 = PKFMA(sp(wv.w), mk(fB.z, fB.w), a0);
        }
        pu.fc.part[w][lane] = a0 + a1;
    }
    __syncthreads();

    // ---- P6: combine quarters + bias + relu (both samples packed)
    if (t < 64) {
        f2 h = pu.fc.part[0][t] + pu.fc.part[1][t]
             + pu.fc.part[2][t] + pu.fc.part[3][t] + sp(f1b[t]);
        pu.fc.hs[t] = PKMAX(h, sp(0.f));
    }
    __syncthreads();

    // ---- P7: fc2 on 64 lanes (16 per output j), shfl-reduce; + BN stats
    if (t < 64) {
        int j = t >> 4, ob = (t & 15) * 4;
        f2 a = sp(0.f);
        #pragma unroll
        for (int o = 0; o < 4; o++)
            a = PKFMA(sp(f2w[j * 64 + ob + o]), pu.fc.hs[ob + o], a);
        #pragma unroll
        for (int m = 1; m < 16; m <<= 1) {
            a.x += __shfl_xor(a.x, m);
            a.y += __shfl_xor(a.y, m);
        }
        if ((t & 15) == 0) {
            a += sp(f2bias[j]);
            feat[((size_t)blockIdx.x * 2 + 0) * 4 + j] = a.x;
            feat[((size_t)blockIdx.x * 2 + 1) * 4 + j] = a.y;
            int g = blockIdx.x & 63;
            atomicAdd(&stats[g * 8 + j], a.x + a.y);
            atomicAdd(&stats[g * 8 + 4 + j], a.x * a.x + a.y * a.y);
        }
    }
}

// ---------------- BN + encoder + U matvec + PauliZ measure ------------------
// 4 lanes per sample (each does 4 rows of the 16x16 matvec, shfl-reduce).
__global__ __launch_bounds__(128) void quantum_kernel(
    const float* __restrict__ feat, const float* __restrict__ Ug,
    const float* __restrict__ stats, const float* __restrict__ bn_g,
    const float* __restrict__ bn_b, float* __restrict__ out, int B)
{
    __shared__ float2 Us[256];
    __shared__ float sm[8];
    int t = threadIdx.x;                  // 128 threads
    for (int i = t; i < 256; i += 128) Us[i] = ((const float2*)Ug)[i];
    if (t < 8) sm[t] = 0.f;
    __syncthreads();
    {   // parallel gather of 64 shards x 8 (index mod 8 preserved by +128)
        float v = stats[t] + stats[t + 128] + stats[t + 256] + stats[t + 384];
        atomicAdd(&sm[t & 7], v);
    }
    __syncthreads();
    int q = t & 3;                        // row-quad within the sample
    int s = blockIdx.x * 32 + (t >> 2);
    float4 fv = ((const float4*)feat)[s];
    float f[4] = {fv.x, fv.y, fv.z, fv.w};
    float cn[4], sn[4];
    float invB = 1.0f / (float)B;
    #pragma unroll
    for (int w = 0; w < 4; w++) {
        float mean = sm[w] * invB;
        float var  = sm[4 + w] * invB - mean * mean;
        float fh = (f[w] - mean) / sqrtf(var + B_EPS) * bn_g[w] + bn_b[w];
        cn[w] = cosf(0.5f * fh);
        sn[w] = sinf(0.5f * fh);
    }
    // encoded product state: s0_k = prod(c/s) * (-i)^popcount(k)
    float re0[16], im0[16];
    #pragma unroll
    for (int k = 0; k < 16; k++) {
        float mag = ((k & 8) ? sn[0] : cn[0]) * ((k & 4) ? sn[1] : cn[1]) *
                    ((k & 2) ? sn[2] : cn[2]) * ((k & 1) ? sn[3] : cn[3]);
        int m = __popc(k) & 3;
        re0[k] = (m == 0) ? mag : (m == 2) ? -mag : 0.f;
        im0[k] = (m == 1) ? -mag : (m == 3) ? mag : 0.f;
    }
    float o0 = 0.f, o1 = 0.f, o2 = 0.f, o3 = 0.f;
    #pragma unroll
    for (int i = 0; i < 4; i++) {
        int r = q * 4 + i;
        float ar = 0.f, ai = 0.f;
        #pragma unroll
        for (int k = 0; k < 16; k++) {
            float2 uu = Us[r * 16 + k];
            ar += uu.x * re0[k] - uu.y * im0[k];
            ai += uu.x * im0[k] + uu.y * re0[k];
        }
        float p = ar * ar + ai * ai;
        o0 += (r & 8) ? -p : p;
        o1 += (r & 4) ? -p : p;
        o2 += (r & 2) ? -p : p;
        o3 += (r & 1) ? -p : p;
    }
    // reduce across the 4-lane group
    o0 += __shfl_xor(o0, 1);  o0 += __shfl_xor(o0, 2);
    o1 += __shfl_xor(o1, 1);  o1 += __shfl_xor(o1, 2);
    o2 += __shfl_xor(o2, 1);  o2 += __shfl_xor(o2, 2);
    o3 += __shfl_xor(o3, 1);  o3 += __shfl_xor(o3, 2);
    if (q == 0) {
        float4 ov = {o0, o1, o2, o3};
        ((float4*)out)[s] = ov;
    }
}

// ---------------------------------------------------------------------------
extern "C" void kernel_launch(void* const* d_in, const int* in_sizes, int n_in,
                              void* d_out, int out_size, void* d_ws, size_t ws_size,
                              hipStream_t stream)
{
    const float* x   = (const float*)d_in[0];
    const float* c1w = (const float*)d_in[1];
    const float* c1b = (const float*)d_in[2];
    const float* c2w = (const float*)d_in[3];
    const float* c2b = (const float*)d_in[4];
    const float* f1w = (const float*)d_in[5];
    const float* f1b = (const float*)d_in[6];
    const float* f2w = (const float*)d_in[7];
    const float* f2b = (const float*)d_in[8];
    const float* bng = (const float*)d_in[9];
    const float* bnb = (const float*)d_in[10];
    const float* rl  = (const float*)d_in[11];
    float* out = (float*)d_out;

    int B = in_sizes[0] / 784;

    float* wsf   = (float*)d_ws;
    float* feat  = wsf;                          // B*4
    float* wT2   = feat + (size_t)B * 4;         // 784*64 (as [k4][64][4])
    float* U     = wT2 + 784 * 64;               // 512 (float2[256])
    float* stats = U + 512;                      // 512 (64 shards x 8)
    float* w2q   = stats + 512;                  // 1536 ([ci][c2][12], q<9 used)

    prep_kernel<<<197, 256, 0, stream>>>(rl, f1w, c2w, U, wT2, w2q, stats);
    conv_kernel<<<B / 2, 256, 0, stream>>>(x, c1w, c1b, w2q, c2b, wT2,
                                           f1b, f2w, f2b, feat, stats);
    quantum_kernel<<<B / 32, 128, 0, stream>>>(feat, U, stats, bng, bnb, out, B);
}

// Round 9
// 179.402 us; speedup vs baseline: 1.1083x; 1.0420x over previous
//
#include <hip/hip_runtime.h>

// ---------------------------------------------------------------------------
// QuantumImageEncoder R20: 4 samples/block (2 f2-pairs, 512 thr, 8 waves).
//  R19 post-mortem: micro-trims neutral; R15 phase structure is the local
//  optimum. Remaining mechanism: fc1 weight stream = 200KB wT2 per block
//  x 4096 blocks = 819MB L2 traffic (~20us of conv's 90). R13 proved halving
//  this pays. R20 halves it again: each block handles 4 samples; fc1 reads
//  each weight float4 ONCE and feeds both pairs (410MB total).
//  Per-thread P2/P3 work identical to R15 (waves 0-3 pair0, 4-7 pair1);
//  P5 walks groups stride-8 across all 8 waves. LDS 2x -> 52.5KB -> 3
//  blocks x 8 waves = 24 waves/CU (same static occupancy as 6x4).
// ---------------------------------------------------------------------------

#define B_EPS 1e-5f

typedef float f2 __attribute__((ext_vector_type(2)));

__device__ __forceinline__ f2 sp(float x)          { f2 r; r.x = x; r.y = x; return r; }
__device__ __forceinline__ f2 mk(float a, float b) { f2 r; r.x = a; r.y = b; return r; }
#define PKFMA(a, b, c) __builtin_elementwise_fma(a, b, c)
#define PKMAX(a, b)    __builtin_elementwise_max(a, b)

// 3-tap conv row update: acc[j] += wp[0..2] * rv[j..j+2]  (packed, 2 samples)
__device__ __forceinline__ void row_fma(f2* acc, const float* wp, const f2* rv)
{
    #pragma unroll
    for (int j = 0; j < 4; j++) {
        acc[j] = PKFMA(sp(wp[0]), rv[j],     acc[j]);
        acc[j] = PKFMA(sp(wp[1]), rv[j + 1], acc[j]);
        acc[j] = PKFMA(sp(wp[2]), rv[j + 2], acc[j]);
    }
}

// load 6 consecutive f2 from 16B-aligned base as 3x b128
__device__ __forceinline__ void load_rv6(f2* rv, const f2* rp)
{
    float4 A = *(const float4*)rp;
    float4 Bv = *(const float4*)(rp + 2);
    float4 Cv = *(const float4*)(rp + 4);
    rv[0] = mk(A.x, A.y);   rv[1] = mk(A.z, A.w);
    rv[2] = mk(Bv.x, Bv.y); rv[3] = mk(Bv.z, Bv.w);
    rv[4] = mk(Cv.x, Cv.y); rv[5] = mk(Cv.z, Cv.w);
}

// ---------------- prep: U build + stats zero + conv2-weight repack (block 0),
// ----------------       fc1_w -> wT2[k4][64][4] (blocks 1..196) -------------
__global__ void prep_kernel(const float* __restrict__ rl,
                            const float* __restrict__ f1w,
                            const float* __restrict__ c2w,
                            float* __restrict__ Uout,
                            float* __restrict__ wT2,
                            float* __restrict__ w2q,
                            float* __restrict__ stats)
{
    if (blockIdx.x == 0) {
        __shared__ float2 U[16][16];
        int t = threadIdx.x;                 // 256 threads
        int r = t >> 4, cc = t & 15;
        U[r][cc] = (r == cc) ? make_float2(1.f, 0.f) : make_float2(0.f, 0.f);
        stats[t] = 0.f;                      // 512-float sharded stats
        stats[t + 256] = 0.f;
        // conv2 weights -> w2q[(ci*16+c2)*12 + q], q<9 valid, float4-aligned
        for (int i = t; i < 16 * 8 * 12; i += 256) {
            int ci = i / 192, rem = i - ci * 192;
            int c2 = rem / 12, qq = rem - c2 * 12;
            w2q[i] = (qq < 9) ? c2w[c2 * 72 + ci * 9 + qq] : 0.f;
        }
        __syncthreads();
        for (int op = 0; op < 30; op++) {
            int kind = op & 3;               // 0=rx,1=ry,2=rz,3=cnot ; wire = op%4
            float2 cur = U[r][cc];
            float2 nv;
            if (kind == 3) {
                float2 part = U[r ^ 8][cc];  // control wire3 (bit 1), target wire0 (bit 8)
                nv = (r & 1) ? part : cur;
            } else {
                int m = 8 >> kind;           // wire w=kind -> bit (3-w)
                float theta = rl[op - (op >> 2)];
                float ch = cosf(0.5f * theta), sh = sinf(0.5f * theta);
                float2 part = U[r ^ m][cc];
                int br = (r & m) ? 1 : 0;
                float2 gc, gp;
                if (kind == 0)      { gc = make_float2(ch, 0.f);           gp = make_float2(0.f, -sh); }
                else if (kind == 1) { gc = make_float2(ch, 0.f);           gp = make_float2(br ? sh : -sh, 0.f); }
                else                { gc = make_float2(ch, br ? sh : -sh); gp = make_float2(0.f, 0.f); }
                nv.x = gc.x*cur.x - gc.y*cur.y + gp.x*part.x - gp.y*part.y;
                nv.y = gc.x*cur.y + gc.y*cur.x + gp.x*part.y + gp.y*part.x;
            }
            __syncthreads();
            U[r][cc] = nv;
            __syncthreads();
        }
        ((float2*)Uout)[t] = U[r][cc];
    } else {
        int id = (blockIdx.x - 1) * 256 + threadIdx.x;
        if (id < 784 * 64) {
            int k = id >> 6, o = id & 63;
            // wT2 float index = (k4*64 + o)*4 + (k&3)
            wT2[(((k >> 2) * 64 + o) << 2) + (k & 3)] = f1w[o * 784 + k];
        }
    }
}

// ---------------- conv backbone + fused fc: 4 samples / block, 8 waves ------
// All activations are f2 = (even sample, odd sample) of a pair. Waves 0-3 own
// pair0 (samples 0,1), waves 4-7 pair1 (samples 2,3). Per-thread P2/P3 work
// identical to the 2-sample R15 kernel.
__global__ __launch_bounds__(512) void conv_kernel(
    const float* __restrict__ x,  const float* __restrict__ c1w,
    const float* __restrict__ c1b, const float* __restrict__ w2q,
    const float* __restrict__ c2b, const float* __restrict__ wT2,
    const float* __restrict__ f1b, const float* __restrict__ f2w,
    const float* __restrict__ f2bias, float* __restrict__ feat,
    float* __restrict__ stats)
{
    __shared__ union alignas(16) {
        f2 xin[2][30 * 32];        // [pair][row][idx]; col c -> idx c+3, halo zeros
        f2 flat[2][784];           // [pair] conv2 pooled output, idx = c2*49+i*7+pc
    } u;
    __shared__ union alignas(16) {
        f2 p1[2][8 * 290];         // [pair][ch][row stride 18][idx]; col c -> idx c+3
        struct { f2 part[8][2][64]; f2 hs[2][64]; } fc;   // p1 dead after P3
    } pu;

    int t = threadIdx.x;
    int w8 = t >> 6, lane = t & 63;
    int pair = w8 >> 2, wp = w8 & 3;

    // conv1 weights for this lane (8 lanes share an address -> L1 broadcast)
    int c1 = lane >> 3;
    float wk1[9];
    #pragma unroll
    for (int q = 0; q < 9; q++) wk1[q] = c1w[c1 * 9 + q];
    float bias1 = c1b[c1];

    // ---- P1: zero xin + p1 (halo correctness)
    {
        float4 z = make_float4(0.f, 0.f, 0.f, 0.f);
        float4* xz = (float4*)u.xin;
        for (int i = t; i < 960; i += 512) xz[i] = z;       // 2x960 f2
        float4* pz = (float4*)pu.p1;
        for (int i = t; i < 2320; i += 512) pz[i] = z;      // 2x2320 f2
    }
    __syncthreads();

    // ---- stage input: 4 samples, pair-interleaved (col c -> idx c+3)
    {
        const float4* xg = (const float4*)(x + (size_t)blockIdx.x * 4 * 784);
        if (t < 392) {
            int pr = t / 196, tt = t - pr * 196;
            float4 v0 = xg[(2 * pr) * 196 + tt];
            float4 v1 = xg[(2 * pr + 1) * 196 + tt];
            int p = 4 * tt, rr = p / 28, cb = p - rr * 28;  // cb in {0,4,...,24}
            f2* dst = &u.xin[pr][(rr + 1) * 32 + cb + 3];
            dst[0] = mk(v0.x, v1.x);
            dst[1] = mk(v0.y, v1.y);
            dst[2] = mk(v0.z, v1.z);
            dst[3] = mk(v0.w, v1.w);
        }
    }
    __syncthreads();

    // ---- P2: conv1 + relu + pool -> p1. wave wp owns pooled rows {wp+4k}
    // of its pair. lane=(c1,g): channel, 4-col group (g<7). 3x b128 per row.
    {
        int g = lane & 7;
        if (g < 7) {
            const f2* xb = &u.xin[pair][4 * g + 2];         // even idx: 16B aligned
            f2* pout = &pu.p1[pair][c1 * 290 + 3];
            #pragma unroll 1
            for (int k = 0; k < 4; k++) {
                int i = wp + 4 * k;                         // pooled row 0..13
                if (i > 13) break;
                f2 o_[2][4];
                #pragma unroll
                for (int dr = 0; dr < 2; dr++)
                    #pragma unroll
                    for (int j = 0; j < 4; j++) o_[dr][j] = sp(bias1);
                #pragma unroll
                for (int q = 0; q < 4; q++) {               // stored row 2i+q
                    f2 rv[6];
                    load_rv6(rv, xb + (2 * i + q) * 32);
                    if (q < 3)  row_fma(o_[0], &wk1[q * 3], rv);        // dr=0, ky=q
                    if (q >= 1) row_fma(o_[1], &wk1[(q - 1) * 3], rv);  // dr=1, ky=q-1
                }
                #pragma unroll
                for (int jj = 0; jj < 2; jj++) {
                    f2 m = PKMAX(PKMAX(o_[0][2 * jj], o_[0][2 * jj + 1]),
                                 PKMAX(o_[1][2 * jj], o_[1][2 * jj + 1]));
                    pout[(i + 1) * 18 + 2 * g + jj] = PKMAX(m, sp(0.f));
                }
            }
        }
    }
    __syncthreads();

    // ---- P3: conv2 + relu + pool -> u.flat (xin dead). wave wp owns pooled
    // rows {wp, wp+4} of its pair. lane=(c2,g2). Weights from w2q (L1).
    {
        int c2 = lane >> 2, g2 = lane & 3;
        float bias2 = c2b[c2];
        const float4* wqb = (const float4*)w2q + c2 * 3;    // + ci*48 per ci
        #pragma unroll 1
        for (int k = 0; k < 2; k++) {
            int i = wp + 4 * k;                             // pooled row 0..6
            if (i > 6) break;
            f2 acc[2][4];
            #pragma unroll
            for (int dr = 0; dr < 2; dr++)
                #pragma unroll
                for (int j = 0; j < 4; j++) acc[dr][j] = sp(bias2);
            float4 wa = wqb[0], wb = wqb[1], wc = wqb[2];
            #pragma unroll 1
            for (int ci = 0; ci < 8; ci++) {
                float wk[9] = {wa.x, wa.y, wa.z, wa.w, wb.x, wb.y, wb.z, wb.w, wc.x};
                if (ci < 7) {                               // prefetch next ci
                    wa = wqb[(ci + 1) * 48];
                    wb = wqb[(ci + 1) * 48 + 1];
                    wc = wqb[(ci + 1) * 48 + 2];
                }
                // even idx base (16B aligned); g2=3 overruns 2 f2 into the
                // next row / next ch row0 -> feeds only discarded pc=7 outputs.
                const f2* pc_ = &pu.p1[pair][ci * 290 + (2 * i) * 18 + 4 * g2 + 2];
                #pragma unroll
                for (int q = 0; q < 4; q++) {               // stored row 2i+q
                    f2 rv[6];
                    load_rv6(rv, pc_ + q * 18);
                    if (q < 3)  row_fma(acc[0], &wk[q * 3], rv);
                    if (q >= 1) row_fma(acc[1], &wk[(q - 1) * 3], rv);
                }
            }
            #pragma unroll
            for (int jj = 0; jj < 2; jj++) {
                int pc = 2 * g2 + jj;
                if (pc < 7) {
                    f2 m = PKMAX(PKMAX(acc[0][2 * jj], acc[0][2 * jj + 1]),
                                 PKMAX(acc[1][2 * jj], acc[1][2 * jj + 1]));
                    u.flat[pair][c2 * 49 + i * 7 + pc] = PKMAX(m, sp(0.f));
                }
            }
        }
    }
    __syncthreads();   // p1 dead from here; pu.fc live

    // ---- P5: fc1 partials. Wave w8 walks groups {g: g==w8 mod 8}; each
    // weight float4 (read ONCE per block) feeds BOTH pairs' chains.
    {
        const f2* flA = u.flat[0];
        const f2* flB = u.flat[1];
        const float4* wp4 = (const float4*)wT2 + lane;      // + g*64 per k4-group
        f2 a0 = sp(0.f), a1 = sp(0.f);
        #pragma unroll 2
        for (int g = w8; g < 196; g += 8) {
            float4 wv = wp4[(size_t)g * 64];
            float4 fA = *(const float4*)&flA[4 * g];
            float4 fB = *(const float4*)&flA[4 * g + 2];
            float4 fC = *(const float4*)&flB[4 * g];
            float4 fD = *(const float4*)&flB[4 * g + 2];
            a0 = PKFMA(sp(wv.x), mk(fA.x, fA.y), a0);
            a0 = PKFMA(sp(wv.y), mk(fA.z, fA.w), a0);
            a0 = PKFMA(sp(wv.z), mk(fB.x, fB.y), a0);
            a0 = PKFMA(sp(wv.w), mk(fB.z, fB.w), a0);
            a1 = PKFMA(sp(wv.x), mk(fC.x, fC.y), a1);
            a1 = PKFMA(sp(wv.y), mk(fC.z, fC.w), a1);
            a1 = PKFMA(sp(wv.z), mk(fD.x, fD.y), a1);
            a1 = PKFMA(sp(wv.w), mk(fD.z, fD.w), a1);
        }
        pu.fc.part[w8][0][lane] = a0;
        pu.fc.part[w8][1][lane] = a1;
    }
    __syncthreads();

    // ---- P6: combine 8 wave-partials + bias + relu (per pair, packed)
    if (t < 128) {
        int p = t >> 6, o = t & 63;
        f2 h = pu.fc.part[0][p][o] + pu.fc.part[1][p][o]
             + pu.fc.part[2][p][o] + pu.fc.part[3][p][o]
             + pu.fc.part[4][p][o] + pu.fc.part[5][p][o]
             + pu.fc.part[6][p][o] + pu.fc.part[7][p][o] + sp(f1b[o]);
        pu.fc.hs[p][o] = PKMAX(h, sp(0.f));
    }
    __syncthreads();

    // ---- P7: fc2 per pair on 64 lanes (16/output), shfl-reduce; + BN stats
    if (t < 128) {
        int p = t >> 6, tt = t & 63;
        int j = tt >> 4, ob = (tt & 15) * 4;
        f2 a = sp(0.f);
        #pragma unroll
        for (int o = 0; o < 4; o++)
            a = PKFMA(sp(f2w[j * 64 + ob + o]), pu.fc.hs[p][ob + o], a);
        #pragma unroll
        for (int m = 1; m < 16; m <<= 1) {
            a.x += __shfl_xor(a.x, m);
            a.y += __shfl_xor(a.y, m);
        }
        if ((tt & 15) == 0) {
            a += sp(f2bias[j]);
            size_t s0 = (size_t)blockIdx.x * 4 + 2 * p;
            feat[s0 * 4 + j]       = a.x;
            feat[(s0 + 1) * 4 + j] = a.y;
            int g = blockIdx.x & 63;
            atomicAdd(&stats[g * 8 + j], a.x + a.y);
            atomicAdd(&stats[g * 8 + 4 + j], a.x * a.x + a.y * a.y);
        }
    }
}

// ---------------- BN + encoder + U matvec + PauliZ measure ------------------
// 4 lanes per sample (each does 4 rows of the 16x16 matvec, shfl-reduce).
__global__ __launch_bounds__(128) void quantum_kernel(
    const float* __restrict__ feat, const float* __restrict__ Ug,
    const float* __restrict__ stats, const float* __restrict__ bn_g,
    const float* __restrict__ bn_b, float* __restrict__ out, int B)
{
    __shared__ float2 Us[256];
    __shared__ float sm[8];
    int t = threadIdx.x;                  // 128 threads
    for (int i = t; i < 256; i += 128) Us[i] = ((const float2*)Ug)[i];
    if (t < 8) sm[t] = 0.f;
    __syncthreads();
    {   // parallel gather of 64 shards x 8 (index mod 8 preserved by +128)
        float v = stats[t] + stats[t + 128] + stats[t + 256] + stats[t + 384];
        atomicAdd(&sm[t & 7], v);
    }
    __syncthreads();
    int q = t & 3;                        // row-quad within the sample
    int s = blockIdx.x * 32 + (t >> 2);
    float4 fv = ((const float4*)feat)[s];
    float f[4] = {fv.x, fv.y, fv.z, fv.w};
    float cn[4], sn[4];
    float invB = 1.0f / (float)B;
    #pragma unroll
    for (int w = 0; w < 4; w++) {
        float mean = sm[w] * invB;
        float var  = sm[4 + w] * invB - mean * mean;
        float fh = (f[w] - mean) / sqrtf(var + B_EPS) * bn_g[w] + bn_b[w];
        cn[w] = cosf(0.5f * fh);
        sn[w] = sinf(0.5f * fh);
    }
    // encoded product state: s0_k = prod(c/s) * (-i)^popcount(k)
    float re0[16], im0[16];
    #pragma unroll
    for (int k = 0; k < 16; k++) {
        float mag = ((k & 8) ? sn[0] : cn[0]) * ((k & 4) ? sn[1] : cn[1]) *
                    ((k & 2) ? sn[2] : cn[2]) * ((k & 1) ? sn[3] : cn[3]);
        int m = __popc(k) & 3;
        re0[k] = (m == 0) ? mag : (m == 2) ? -mag : 0.f;
        im0[k] = (m == 1) ? -mag : (m == 3) ? mag : 0.f;
    }
    float o0 = 0.f, o1 = 0.f, o2 = 0.f, o3 = 0.f;
    #pragma unroll
    for (int i = 0; i < 4; i++) {
        int r = q * 4 + i;
        float ar = 0.f, ai = 0.f;
        #pragma unroll
        for (int k = 0; k < 16; k++) {
            float2 uu = Us[r * 16 + k];
            ar += uu.x * re0[k] - uu.y * im0[k];
            ai += uu.x * im0[k] + uu.y * re0[k];
        }
        float p = ar * ar + ai * ai;
        o0 += (r & 8) ? -p : p;
        o1 += (r & 4) ? -p : p;
        o2 += (r & 2) ? -p : p;
        o3 += (r & 1) ? -p : p;
    }
    // reduce across the 4-lane group
    o0 += __shfl_xor(o0, 1);  o0 += __shfl_xor(o0, 2);
    o1 += __shfl_xor(o1, 1);  o1 += __shfl_xor(o1, 2);
    o2 += __shfl_xor(o2, 1);  o2 += __shfl_xor(o2, 2);
    o3 += __shfl_xor(o3, 1);  o3 += __shfl_xor(o3, 2);
    if (q == 0) {
        float4 ov = {o0, o1, o2, o3};
        ((float4*)out)[s] = ov;
    }
}

// ---------------------------------------------------------------------------
extern "C" void kernel_launch(void* const* d_in, const int* in_sizes, int n_in,
                              void* d_out, int out_size, void* d_ws, size_t ws_size,
                              hipStream_t stream)
{
    const float* x   = (const float*)d_in[0];
    const float* c1w = (const float*)d_in[1];
    const float* c1b = (const float*)d_in[2];
    const float* c2w = (const float*)d_in[3];
    const float* c2b = (const float*)d_in[4];
    const float* f1w = (const float*)d_in[5];
    const float* f1b = (const float*)d_in[6];
    const float* f2w = (const float*)d_in[7];
    const float* f2b = (const float*)d_in[8];
    const float* bng = (const float*)d_in[9];
    const float* bnb = (const float*)d_in[10];
    const float* rl  = (const float*)d_in[11];
    float* out = (float*)d_out;

    int B = in_sizes[0] / 784;

    float* wsf   = (float*)d_ws;
    float* feat  = wsf;                          // B*4
    float* wT2   = feat + (size_t)B * 4;         // 784*64 (as [k4][64][4])
    float* U     = wT2 + 784 * 64;               // 512 (float2[256])
    float* stats = U + 512;                      // 512 (64 shards x 8)
    float* w2q   = stats + 512;                  // 1536 ([ci][c2][12], q<9 used)

    prep_kernel<<<197, 256, 0, stream>>>(rl, f1w, c2w, U, wT2, w2q, stats);
    conv_kernel<<<B / 4, 512, 0, stream>>>(x, c1w, c1b, w2q, c2b, wT2,
                                           f1b, f2w, f2b, feat, stats);
    quantum_kernel<<<B / 32, 128, 0, stream>>>(feat, U, stats, bng, bnb, out, B);
}